// Round 7
// baseline (138.186 us; speedup 1.0000x reference)
//
#include <hip/hip_runtime.h>
#include <math.h>

#define EPSC 1e-6f
#define THETAC 1e-3f
#define C1C 1e-4f
#define C2C 9e-4f
#define DEN_EPS 1e-12f

constexpr int Bn = 4, Cn = 16, Hn = 512, Wn = 512;
constexpr int HW = Hn * Wn;          // 262144 = 2^18
constexpr int NP = Bn * HW;          // 1048576
constexpr int TS = 32, RAD = 5, K = 11;
constexpr int HALO = TS + 2 * RAD;   // 42
constexpr int PITCH = 43;            // k_ssim halo pitch
constexpr int HP = 33;               // horizontal-sum pitch (linear, conflict-free)
constexpr int ASZ = HALO * PITCH;    // 1806
constexpr int HSZ = HALO * HP;       // 1386
constexpr int tiles_x = Wn / TS;     // 16
constexpr int NT = tiles_x * (Hn / TS); // 256 (k_ssim grid)

// ---- channel-pass geometry: 32x64 output tile, 48x74 window ----
constexpr int CTH = 64;              // output tile height
constexpr int CWIN = CTH + 10;       // 74 window rows
constexpr int CPW = 49;              // window pitch (48 + 1)
constexpr int CSSZ = CWIN * CPW;     // 3626
constexpr int CHSZ = CWIN * HP;      // 2442
constexpr int NT2 = 16 * (Hn / CTH); // 128 tiles

__device__ __forceinline__ int refl(int i, int n) {
    if (i < 0) i = -i;
    if (i >= n) i = 2 * n - 2 - i;
    return i;
}

__device__ __forceinline__ int swz_tile(int x) { return (x & 7) * (NT / 8) + (x >> 3); }
__device__ __forceinline__ int swz_tile2(int x) { return (x & 7) * (NT2 / 8) + (x >> 3); }

__device__ __forceinline__ unsigned int bf16pack(float a, float b) {
    unsigned int ua = __float_as_uint(a), ub = __float_as_uint(b);
    ua += 0x7FFFu + ((ua >> 16) & 1u);
    ub += 0x7FFFu + ((ub >> 16) & 1u);
    return (ua >> 16) | (ub & 0xFFFF0000u);
}
__device__ __forceinline__ float bflo(unsigned int v) { return __uint_as_float(v << 16); }
__device__ __forceinline__ float bfhi(unsigned int v) { return __uint_as_float(v & 0xFFFF0000u); }

// vbox8: sliding vertical box-11 over linear pitch-33 h, 8 output rows
__device__ __forceinline__ void vbox8(const float* h, int x, int r0, float m[8]) {
    const float inv = 1.f / 121.f;
    const float* hb = h + r0 * HP + x;
    float s = hb[0];
#pragma unroll
    for (int dy = 1; dy < K; ++dy) s += hb[dy * HP];
    m[0] = s * inv;
#pragma unroll
    for (int j = 1; j < 8; ++j) {
        s += hb[(j + 10) * HP] - hb[(j - 1) * HP];
        m[j] = s * inv;
    }
}

// ---------------- K1: merged Xs (channel mean) + chi (+partial reductions) ----------------
__global__ void __launch_bounds__(256) k_xschi(
        const float* __restrict__ X, const float* __restrict__ G,
        float* __restrict__ Xs, float* __restrict__ chi,
        float* __restrict__ psum, float* __restrict__ pmin) {
    int t = threadIdx.x;
    if (blockIdx.x < 1024) {
        constexpr int HW4 = HW / 4;
        int i = blockIdx.x * 256 + t;
        int b = i / HW4, off = i - b * HW4;
        const float4* xp = (const float4*)(X + (size_t)b * Cn * HW) + off;
        float4 s = make_float4(0.f, 0.f, 0.f, 0.f);
#pragma unroll
        for (int c = 0; c < Cn; ++c) {
            float4 v = xp[(size_t)c * HW4];
            s.x += v.x; s.y += v.y; s.z += v.z; s.w += v.w;
        }
        const float sc = 1.0f / Cn;
        s.x *= sc; s.y *= sc; s.z *= sc; s.w *= sc;
        ((float4*)Xs)[i] = s;
        return;
    }
    __shared__ float ssum[256], smin[256];
    int bid = blockIdx.x - 1024;
    int base = bid * 1024;
    float ls = 0.f, lm = 1e30f;
#pragma unroll
    for (int k = 0; k < 4; ++k) {
        int p = base + t + k * 256;
        int off = p & (HW - 1);
        int y = off / Wn, x = off & (Wn - 1);
        float g = G[p];
        float gx = (x < Wn - 1) ? G[p + 1] - g : 0.f;
        float gy = (y < Hn - 1) ? G[p + Wn] - g : 0.f;
        float c = sqrtf(gx * gx + gy * gy + EPSC);
        chi[p] = c;
        ls += c;
        lm = fminf(lm, c);
    }
    ssum[t] = ls; smin[t] = lm;
    __syncthreads();
    for (int s = 128; s > 0; s >>= 1) {
        if (t < s) { ssum[t] += ssum[t + s]; smin[t] = fminf(smin[t], smin[t + s]); }
        __syncthreads();
    }
    if (t == 0) { psum[bid] = ssum[0]; pmin[bid] = smin[0]; }
}

// k_ssim helpers: hbox over 2 planes (x|g), optionally squared; 16-wide chunks
template <bool SQ>
__device__ __forceinline__ void ss_hbox2(const float* arrs, float* hs, int t) {
    if (t < 168) {
        int pl = t / 84, rem = t - pl * 84;
        int y = rem >> 1, xh = (rem & 1) << 4;
        const float* src = arrs + pl * ASZ + y * PITCH + xh;
        float* hd = hs + pl * HSZ + y * HP + xh;
        float v = src[0];
        float s = SQ ? v * v : v;
#pragma unroll
        for (int dx = 1; dx < K; ++dx) { float u = src[dx]; s += SQ ? u * u : u; }
        hd[0] = s;
#pragma unroll
        for (int j = 1; j < 16; ++j) {
            float un = src[j + 10], uo = src[j - 1];
            s += (SQ ? un * un : un) - (SQ ? uo * uo : uo);
            hd[j] = s;
        }
    }
}

__device__ __forceinline__ void ss_vbox(const float* hs, int x, int r0, float m[4]) {
    const float inv_area = 1.f / (float)(K * K);
    const float* hb = hs + r0 * HP + x;
    float s = hb[0];
#pragma unroll
    for (int dy = 1; dy < K; ++dy) s += hb[dy * HP];
    m[0] = s * inv_area;
#pragma unroll
    for (int j = 1; j < 4; ++j) {
        s += hb[(j + 10) * HP] - hb[(j - 1) * HP];
        m[j] = s * inv_area;
    }
}

// ---------------- K3: merged ssim r=5 & r=1 + plane outputs + reductions ----------------
__global__ void __launch_bounds__(256) k_ssim(
        const float* __restrict__ Xs, const float* __restrict__ G,
        float* __restrict__ muG, float* __restrict__ varGr, float* __restrict__ taur,
        float* __restrict__ chig, float* __restrict__ nu,
        float* __restrict__ ps1, float* __restrict__ ps2) {
    __shared__ float arrs[2 * ASZ];   // sx, sg halos only
    __shared__ float hs[2 * HSZ];
    float* red1 = hs;                 // aliased after last vbox
    float* red2 = hs + HSZ;
    int t = threadIdx.x;
    int b = blockIdx.y;
    int tile = swz_tile(blockIdx.x);
    int tx0 = (tile % tiles_x) * TS, ty0 = (tile / tiles_x) * TS;
    const float* Xp = Xs + (size_t)b * HW;
    const float* Gp = G + (size_t)b * HW;
    for (int i = t; i < HALO * HALO; i += 256) {
        int ly = i / HALO, lx = i - ly * HALO;
        int gy = refl(ty0 - RAD + ly, Hn), gx = refl(tx0 - RAD + lx, Wn);
        int o = ly * PITCH + lx;
        arrs[o] = Xp[gy * Wn + gx];
        arrs[ASZ + o] = Gp[gy * Wn + gx];
    }
    __syncthreads();

    int x = t & 31, g = t >> 5, r0 = g * 4;
    float acc[5][4];
    ss_hbox2<false>(arrs, hs, t);
    __syncthreads();
    ss_vbox(hs, x, r0, acc[0]);
    ss_vbox(hs + HSZ, x, r0, acc[1]);
    __syncthreads();
    ss_hbox2<true>(arrs, hs, t);
    __syncthreads();
    ss_vbox(hs, x, r0, acc[2]);
    ss_vbox(hs + HSZ, x, r0, acc[3]);
    __syncthreads();
    if (t < 168) {
        int y = t >> 2, c = t & 3;
        const float* sx = arrs + y * PITCH + 8 * c;
        const float* sg = arrs + ASZ + y * PITCH + 8 * c;
        float* hd = hs + y * HP + 8 * c;
        float s = sx[0] * sg[0];
#pragma unroll
        for (int dx = 1; dx < K; ++dx) s += sx[dx] * sg[dx];
        hd[0] = s;
#pragma unroll
        for (int j = 1; j < 8; ++j) {
            s += sx[j + 10] * sg[j + 10] - sx[j - 1] * sg[j - 1];
            hd[j] = s;
        }
    }
    __syncthreads();
    ss_vbox(hs, x, r0, acc[4]);

    float m1[5][4];
#pragma unroll
    for (int p = 0; p < 5; ++p) {
        float h3[6];
#pragma unroll
        for (int j = 0; j < 6; ++j) {
            int bb = (r0 + 4 + j) * PITCH + (x + 4);
            float s = 0.f;
#pragma unroll
            for (int i = 0; i < 3; ++i) {
                float vx = arrs[bb + i], vg = arrs[ASZ + bb + i];
                float v = (p == 0) ? vx : (p == 1) ? vg : (p == 2) ? vx * vx
                          : (p == 3) ? vg * vg : vx * vg;
                s += v;
            }
            h3[j] = s;
        }
#pragma unroll
        for (int j = 0; j < 4; ++j)
            m1[p][j] = (h3[j] + h3[j + 1] + h3[j + 2]) * (1.f / 9.f);
    }

    float l1 = 0.f, l2 = 0.f;
    float outv[5][4];
#pragma unroll
    for (int j = 0; j < 4; ++j) {
        float mux = acc[0][j], mug = acc[1][j], mxx = acc[2][j], mgg = acc[3][j], mxy = acc[4][j];
        float sx2 = fmaxf(mxx - mux * mux, 0.f);
        float sg2 = fmaxf(mgg - mug * mug, 0.f);
        float sxy = mxy - mux * mug;
        float num = (2.f * mux * mug + C1C) * (2.f * sxy + C2C);
        float den = (mux * mux + mug * mug + C1C) * (sx2 + sg2 + C2C);
        float tr_ = fminf(fmaxf((num / (den + DEN_EPS) + 1.f) * 0.5f, 0.f), 1.f);

        float n0 = m1[0][j], n1 = m1[1][j], n2 = m1[2][j], n3 = m1[3][j], n4 = m1[4][j];
        float sx21 = fmaxf(n2 - n0 * n0, 0.f);
        float sg21 = fmaxf(n3 - n1 * n1, 0.f);
        float sxy1 = n4 - n0 * n1;
        float num1 = (2.f * n0 * n1 + C1C) * (2.f * sxy1 + C2C);
        float den1 = (n0 * n0 + n1 * n1 + C1C) * (sx21 + sg21 + C2C);
        float t1_ = fminf(fmaxf((num1 / (den1 + DEN_EPS) + 1.f) * 0.5f, 0.f), 1.f);

        float chig_ = sqrtf(sg21 + EPSC) * sqrtf(sg2 + EPSC);
        float nu_ = fmaxf(t1_ * tr_, 0.f);
        outv[0][j] = mug; outv[1][j] = sg2; outv[2][j] = tr_;
        outv[3][j] = chig_; outv[4][j] = nu_;
        l1 += 1.f / (chig_ + EPSC);
        l2 += 1.f / (nu_ + THETAC);
    }
#pragma unroll
    for (int j = 0; j < 4; ++j) {
        int gp = b * HW + (ty0 + r0 + j) * Wn + (tx0 + x);
        muG[gp] = outv[0][j];
        varGr[gp] = outv[1][j];
        taur[gp] = outv[2][j];
        chig[gp] = outv[3][j];
        nu[gp] = outv[4][j];
    }
    __syncthreads();
    red1[t] = l1; red2[t] = l2;
    __syncthreads();
    for (int s = 128; s > 0; s >>= 1) {
        if (t < s) { red1[t] += red1[t + s]; red2[t] += red2[t + s]; }
        __syncthreads();
    }
    if (t == 0) {
        ps1[b * NT + blockIdx.x] = red1[0];
        ps2[b * NT + blockIdx.x] = red2[0];
    }
}

// ---------------- K red: merged chired + nured ----------------
__global__ void __launch_bounds__(256) k_red(
        const float* __restrict__ psum, const float* __restrict__ pmin,
        const float* __restrict__ s1, const float* __restrict__ s2,
        float* __restrict__ sc) {
    __shared__ float a1[256], a2[256];
    int t = threadIdx.x;
    if (blockIdx.x < 4) {
        int b = blockIdx.x;
        a1[t] = psum[b * 256 + t];
        a2[t] = pmin[b * 256 + t];
        __syncthreads();
        for (int s = 128; s > 0; s >>= 1) {
            if (t < s) { a1[t] += a1[t + s]; a2[t] = fminf(a2[t], a2[t + s]); }
            __syncthreads();
        }
        if (t == 0) {
            float mu = a1[0] / (float)HW;
            sc[b] = mu;
            sc[4 + b] = fmaxf(mu - a2[0], EPSC);
        }
    } else {
        int b = blockIdx.x - 4;
        a1[t] = s1[b * 256 + t];
        a2[t] = s2[b * 256 + t];
        __syncthreads();
        for (int s = 128; s > 0; s >>= 1) {
            if (t < s) { a1[t] += a1[t + s]; a2[t] += a2[t + s]; }
            __syncthreads();
        }
        if (t == 0) {
            sc[8 + b] = a1[0] / (float)HW;
            sc[12 + b] = a2[0] / (float)HW;
        }
    }
}

// ---------------- K4: per-pixel packed (P, D, muG) plane, 4-wide ----------------
__global__ void __launch_bounds__(256) k_pd(
        const float* __restrict__ chi, const float* __restrict__ chig,
        const float* __restrict__ nu, const float* __restrict__ taur,
        const float* __restrict__ vr, const float* __restrict__ muG,
        const float* __restrict__ sc, float4* __restrict__ PDM) {
    int i = blockIdx.x * 256 + threadIdx.x;   // i < NP/4
    int p0 = i * 4;
    int b = p0 >> 18;
    float mu = sc[b], eta = sc[4 + b], imc = sc[8 + b], imn = sc[12 + b];
    float4 c4 = ((const float4*)chi)[i];
    float4 cg4 = ((const float4*)chig)[i];
    float4 nu4 = ((const float4*)nu)[i];
    float4 tr4 = ((const float4*)taur)[i];
    float4 vr4 = ((const float4*)vr)[i];
    float4 mg4 = ((const float4*)muG)[i];
    float cc[4] = {c4.x, c4.y, c4.z, c4.w};
    float gg[4] = {cg4.x, cg4.y, cg4.z, cg4.w};
    float nn[4] = {nu4.x, nu4.y, nu4.z, nu4.w};
    float tt[4] = {tr4.x, tr4.y, tr4.z, tr4.w};
    float vv[4] = {vr4.x, vr4.y, vr4.z, vr4.w};
    float mm[4] = {mg4.x, mg4.y, mg4.z, mg4.w};
#pragma unroll
    for (int j = 0; j < 4; ++j) {
        float gamma = 1.f / (1.f + expf(-eta * (cc[j] - mu)));
        float GG = (gg[j] + EPSC) * imc;
        float w_e = 1.0f / (GG + EPSC);
        float GS = (nn[j] + THETAC) * imn;
        float w_s = gamma / (GS + EPSC);
        float P = w_e * gamma + w_s * tt[j];
        float D = vv[j] + EPSC + w_e + w_s + EPSC;
        PDM[p0 + j] = make_float4(P, D, mm[j], 0.f);
    }
}

// ---------------- K5: per-channel a,b (32x64 tile, 2 barriers, bf16 AB out) ----------------
__global__ void __launch_bounds__(256) k_ab(
        const float* __restrict__ X, const float* __restrict__ G,
        const float4* __restrict__ PDM, unsigned int* __restrict__ AB) {
    __shared__ float s0[CSSZ], s1[CSSZ];   // X, X*G (48-wide window, pitch 49)
    __shared__ float h0[CHSZ], h1[CHSZ];
    int t = threadIdx.x;
    int pc = blockIdx.y, b = pc >> 4;
    int tile = swz_tile2(blockIdx.x);
    int tx0 = (tile & 15) * TS, ty0 = (tile >> 4) * CTH;
    int x = t & 31, wg = t >> 5, r0 = wg * 8;

    const float* Xp = X + (size_t)pc * HW;
    const float* Gp = G + (size_t)b * HW;
    bool xin = (tx0 >= 32 && tx0 <= 448);
    if (xin) {
        for (int u = t; u < CWIN * 12; u += 256) {
            int ly = u / 12, k = u - ly * 12;
            int gy = refl(ty0 - 5 + ly, Hn);
            int gi = gy * Wn + (tx0 - 8) + 4 * k;
            float4 xv = *(const float4*)(Xp + gi);
            float4 gv = *(const float4*)(Gp + gi);
            int o = ly * CPW + 4 * k;
            s0[o] = xv.x; s0[o + 1] = xv.y; s0[o + 2] = xv.z; s0[o + 3] = xv.w;
            s1[o] = xv.x * gv.x; s1[o + 1] = xv.y * gv.y;
            s1[o + 2] = xv.z * gv.z; s1[o + 3] = xv.w * gv.w;
        }
    } else {
        for (int u = t; u < CWIN * 48; u += 256) {
            int ly = u / 48, l = u - ly * 48;
            int gy = refl(ty0 - 5 + ly, Hn), gx = refl(tx0 - 8 + l, Wn);
            float xv = Xp[gy * Wn + gx], gv = Gp[gy * Wn + gx];
            s0[ly * CPW + l] = xv;
            s1[ly * CPW + l] = xv * gv;
        }
    }
    // prefetch epilogue operands (latency hides under hbox/vbox)
    const float4* Pp = PDM + (size_t)b * HW;
    int pbase = (ty0 + r0) * Wn + tx0 + x;
    float4 pdm[8];
#pragma unroll
    for (int j = 0; j < 8; ++j) pdm[j] = Pp[pbase + j * Wn];
    __syncthreads();

    // hbox both planes: 296 tasks, 16-wide sliding chunks
    for (int u = t; u < 2 * CWIN * 2; u += 256) {
        int pl = u / (2 * CWIN), rem = u - pl * (2 * CWIN);
        int y = rem >> 1, xh = (rem & 1) << 4;
        const float* src = (pl ? s1 : s0) + y * CPW + xh + 3;
        float* dst = (pl ? h1 : h0) + y * HP + xh;
        float acc = src[0];
#pragma unroll
        for (int dx = 1; dx < K; ++dx) acc += src[dx];
        dst[0] = acc;
#pragma unroll
        for (int j = 1; j < 16; ++j) {
            acc += src[j + 10] - src[j - 1];
            dst[j] = acc;
        }
    }
    __syncthreads();

    float mx[8], mxg[8];
    vbox8(h0, x, r0, mx);
    vbox8(h1, x, r0, mxg);

    unsigned int* Ap = AB + (size_t)pc * HW;
#pragma unroll
    for (int j = 0; j < 8; ++j) {
        float a = (mxg[j] - pdm[j].z * mx[j] + pdm[j].x) / pdm[j].y;
        float bb = mx[j] - a * pdm[j].z;
        Ap[pbase + j * Wn] = bf16pack(a, bb);
    }
}

// ---------------- K6: out = box11(a)*G + box11(b) (packed-uint LDS window) ----------------
__global__ void __launch_bounds__(256) k_out(
        const unsigned int* __restrict__ AB, const float* __restrict__ G,
        float* __restrict__ out) {
    __shared__ unsigned int su[CSSZ];   // packed (a,b)
    __shared__ float h0[CHSZ], h1[CHSZ];
    int t = threadIdx.x;
    int pc = blockIdx.y, b = pc >> 4;
    int tile = swz_tile2(blockIdx.x);
    int tx0 = (tile & 15) * TS, ty0 = (tile >> 4) * CTH;
    int x = t & 31, wg = t >> 5, r0 = wg * 8;

    const unsigned int* Ap = AB + (size_t)pc * HW;
    bool xin = (tx0 >= 32 && tx0 <= 448);
    if (xin) {
        for (int u = t; u < CWIN * 12; u += 256) {
            int ly = u / 12, k = u - ly * 12;
            int gy = refl(ty0 - 5 + ly, Hn);
            uint4 v = *(const uint4*)(Ap + gy * Wn + (tx0 - 8) + 4 * k);
            int o = ly * CPW + 4 * k;
            su[o] = v.x; su[o + 1] = v.y; su[o + 2] = v.z; su[o + 3] = v.w;
        }
    } else {
        for (int u = t; u < CWIN * 48; u += 256) {
            int ly = u / 48, l = u - ly * 48;
            int gy = refl(ty0 - 5 + ly, Hn), gx = refl(tx0 - 8 + l, Wn);
            su[ly * CPW + l] = Ap[gy * Wn + gx];
        }
    }
    // prefetch G for epilogue
    const float* Gp = G + (size_t)b * HW;
    int pbase = (ty0 + r0) * Wn + tx0 + x;
    float gv[8];
#pragma unroll
    for (int j = 0; j < 8; ++j) gv[j] = Gp[pbase + j * Wn];
    __syncthreads();

    // hbox both planes (unpack bf16 at tap time): 296 tasks
    for (int u = t; u < 2 * CWIN * 2; u += 256) {
        int pl = u / (2 * CWIN), rem = u - pl * (2 * CWIN);
        int y = rem >> 1, xh = (rem & 1) << 4;
        const unsigned int* src = su + y * CPW + xh + 3;
        float* dst = (pl ? h1 : h0) + y * HP + xh;
        if (pl == 0) {
            float acc = bflo(src[0]);
#pragma unroll
            for (int dx = 1; dx < K; ++dx) acc += bflo(src[dx]);
            dst[0] = acc;
#pragma unroll
            for (int j = 1; j < 16; ++j) {
                acc += bflo(src[j + 10]) - bflo(src[j - 1]);
                dst[j] = acc;
            }
        } else {
            float acc = bfhi(src[0]);
#pragma unroll
            for (int dx = 1; dx < K; ++dx) acc += bfhi(src[dx]);
            dst[0] = acc;
#pragma unroll
            for (int j = 1; j < 16; ++j) {
                acc += bfhi(src[j + 10]) - bfhi(src[j - 1]);
                dst[j] = acc;
            }
        }
    }
    __syncthreads();

    float ma[8], mb[8];
    vbox8(h0, x, r0, ma);
    vbox8(h1, x, r0, mb);

    float* op = out + (size_t)pc * HW;
#pragma unroll
    for (int j = 0; j < 8; ++j)
        op[pbase + j * Wn] = ma[j] * gv[j] + mb[j];
}

extern "C" void kernel_launch(void* const* d_in, const int* in_sizes, int n_in,
                              void* d_out, int out_size, void* d_ws, size_t ws_size,
                              hipStream_t stream) {
    const float* X = (const float*)d_in[0];
    const float* G = (const float*)d_in[1];
    float* out = (float*)d_out;
    float* ws = (float*)d_ws;

    float* Xs   = ws + 0 * (size_t)NP;
    float* chi  = ws + 1 * (size_t)NP;
    float* taur = ws + 2 * (size_t)NP;
    float* vr   = ws + 3 * (size_t)NP;
    float* muG  = ws + 4 * (size_t)NP;
    float* chig = ws + 5 * (size_t)NP;
    float* nu   = ws + 6 * (size_t)NP;
    float4* PDM = (float4*)(ws + 7 * (size_t)NP);            // 4*NP floats
    unsigned int* AB = (unsigned int*)(ws + 11 * (size_t)NP); // NX uints
    float* psum = ws + 43 * (size_t)NP;
    float* pmin = psum + 1024;
    float* ps1  = pmin + 1024;
    float* ps2  = ps1 + 1024;
    float* sc   = ps2 + 1024;   // 16 scalars

    dim3 blk(256);
    k_xschi<<<2048, blk, 0, stream>>>(X, G, Xs, chi, psum, pmin);

    dim3 gplane(NT, Bn);
    k_ssim<<<gplane, blk, 0, stream>>>(Xs, G, muG, vr, taur, chig, nu, ps1, ps2);
    k_red<<<8, blk, 0, stream>>>(psum, pmin, ps1, ps2, sc);
    k_pd<<<(NP / 4) / 256, blk, 0, stream>>>(chi, chig, nu, taur, vr, muG, sc, PDM);

    dim3 gchan(NT2, Bn * Cn);
    k_ab<<<gchan, blk, 0, stream>>>(X, G, PDM, AB);
    k_out<<<gchan, blk, 0, stream>>>(AB, G, out);
}

// Round 8
// 133.675 us; speedup vs baseline: 1.0337x; 1.0337x over previous
//
#include <hip/hip_runtime.h>
#include <math.h>

#define EPSC 1e-6f
#define THETAC 1e-3f
#define C1C 1e-4f
#define C2C 9e-4f
#define DEN_EPS 1e-12f

constexpr int Bn = 4, Cn = 16, Hn = 512, Wn = 512;
constexpr int HW = Hn * Wn;          // 262144 = 2^18
constexpr int NP = Bn * HW;          // 1048576
constexpr int TS = 32, RAD = 5, K = 11;
constexpr int HALO = TS + 2 * RAD;   // 42
constexpr int PITCH = 43;            // k_ssim halo pitch
constexpr int HP = 33;               // horizontal-sum pitch (linear, conflict-free)
constexpr int ASZ = HALO * PITCH;    // 1806
constexpr int HSZ = HALO * HP;       // 1386
constexpr int tiles_x = Wn / TS;     // 16
constexpr int NT = tiles_x * (Hn / TS); // 256

// channel-pass geometry: compact 42-wide window, pitch 43
constexpr int CP = 43;
constexpr int CS = HALO * CP;        // 1806

__device__ __forceinline__ int refl(int i, int n) {
    if (i < 0) i = -i;
    if (i >= n) i = 2 * n - 2 - i;
    return i;
}

__device__ __forceinline__ int swz_tile(int x) { return (x & 7) * (NT / 8) + (x >> 3); }

__device__ __forceinline__ unsigned int bf16pack(float a, float b) {
    unsigned int ua = __float_as_uint(a), ub = __float_as_uint(b);
    ua += 0x7FFFu + ((ua >> 16) & 1u);
    ub += 0x7FFFu + ((ub >> 16) & 1u);
    return (ua >> 16) | (ub & 0xFFFF0000u);
}
__device__ __forceinline__ float bflo(unsigned int v) { return __uint_as_float(v << 16); }
__device__ __forceinline__ float bfhi(unsigned int v) { return __uint_as_float(v & 0xFFFF0000u); }

// vbox4 over linear pitch-33 h
__device__ __forceinline__ void vbox4(const float* h, int x, int r0, float m[4]) {
    const float inv = 1.f / 121.f;
    const float* hb = h + r0 * HP + x;
    float s = hb[0];
#pragma unroll
    for (int dy = 1; dy < K; ++dy) s += hb[dy * HP];
    m[0] = s * inv;
#pragma unroll
    for (int j = 1; j < 4; ++j) {
        s += hb[(j + 10) * HP] - hb[(j - 1) * HP];
        m[j] = s * inv;
    }
}

// ---------------- K1: merged Xs (channel mean) + chi (+partial reductions) ----------------
__global__ void __launch_bounds__(256) k_xschi(
        const float* __restrict__ X, const float* __restrict__ G,
        float* __restrict__ Xs, float* __restrict__ chi,
        float* __restrict__ psum, float* __restrict__ pmin) {
    int t = threadIdx.x;
    if (blockIdx.x < 1024) {
        constexpr int HW4 = HW / 4;
        int i = blockIdx.x * 256 + t;
        int b = i / HW4, off = i - b * HW4;
        const float4* xp = (const float4*)(X + (size_t)b * Cn * HW) + off;
        float4 s = make_float4(0.f, 0.f, 0.f, 0.f);
#pragma unroll
        for (int c = 0; c < Cn; ++c) {
            float4 v = xp[(size_t)c * HW4];
            s.x += v.x; s.y += v.y; s.z += v.z; s.w += v.w;
        }
        const float sc = 1.0f / Cn;
        s.x *= sc; s.y *= sc; s.z *= sc; s.w *= sc;
        ((float4*)Xs)[i] = s;
        return;
    }
    __shared__ float ssum[256], smin[256];
    int bid = blockIdx.x - 1024;
    int base = bid * 1024;
    float ls = 0.f, lm = 1e30f;
#pragma unroll
    for (int k = 0; k < 4; ++k) {
        int p = base + t + k * 256;
        int off = p & (HW - 1);
        int y = off / Wn, x = off & (Wn - 1);
        float g = G[p];
        float gx = (x < Wn - 1) ? G[p + 1] - g : 0.f;
        float gy = (y < Hn - 1) ? G[p + Wn] - g : 0.f;
        float c = sqrtf(gx * gx + gy * gy + EPSC);
        chi[p] = c;
        ls += c;
        lm = fminf(lm, c);
    }
    ssum[t] = ls; smin[t] = lm;
    __syncthreads();
    for (int s = 128; s > 0; s >>= 1) {
        if (t < s) { ssum[t] += ssum[t + s]; smin[t] = fminf(smin[t], smin[t + s]); }
        __syncthreads();
    }
    if (t == 0) { psum[bid] = ssum[0]; pmin[bid] = smin[0]; }
}

// k_ssim helpers
template <bool SQ>
__device__ __forceinline__ void ss_hbox2(const float* arrs, float* hs, int t) {
    if (t < 168) {
        int pl = t / 84, rem = t - pl * 84;
        int y = rem >> 1, xh = (rem & 1) << 4;
        const float* src = arrs + pl * ASZ + y * PITCH + xh;
        float* hd = hs + pl * HSZ + y * HP + xh;
        float v = src[0];
        float s = SQ ? v * v : v;
#pragma unroll
        for (int dx = 1; dx < K; ++dx) { float u = src[dx]; s += SQ ? u * u : u; }
        hd[0] = s;
#pragma unroll
        for (int j = 1; j < 16; ++j) {
            float un = src[j + 10], uo = src[j - 1];
            s += (SQ ? un * un : un) - (SQ ? uo * uo : uo);
            hd[j] = s;
        }
    }
}

__device__ __forceinline__ void ss_vbox(const float* hs, int x, int r0, float m[4]) {
    const float inv_area = 1.f / (float)(K * K);
    const float* hb = hs + r0 * HP + x;
    float s = hb[0];
#pragma unroll
    for (int dy = 1; dy < K; ++dy) s += hb[dy * HP];
    m[0] = s * inv_area;
#pragma unroll
    for (int j = 1; j < 4; ++j) {
        s += hb[(j + 10) * HP] - hb[(j - 1) * HP];
        m[j] = s * inv_area;
    }
}

// ---------------- K3: merged ssim r=5 & r=1 + plane outputs + reductions ----------------
__global__ void __launch_bounds__(256) k_ssim(
        const float* __restrict__ Xs, const float* __restrict__ G,
        float* __restrict__ muG, float* __restrict__ varGr, float* __restrict__ taur,
        float* __restrict__ chig, float* __restrict__ nu,
        float* __restrict__ ps1, float* __restrict__ ps2) {
    __shared__ float arrs[2 * ASZ];
    __shared__ float hs[2 * HSZ];
    float* red1 = hs;
    float* red2 = hs + HSZ;
    int t = threadIdx.x;
    int b = blockIdx.y;
    int tile = swz_tile(blockIdx.x);
    int tx0 = (tile % tiles_x) * TS, ty0 = (tile / tiles_x) * TS;
    const float* Xp = Xs + (size_t)b * HW;
    const float* Gp = G + (size_t)b * HW;
    for (int i = t; i < HALO * HALO; i += 256) {
        int ly = i / HALO, lx = i - ly * HALO;
        int gy = refl(ty0 - RAD + ly, Hn), gx = refl(tx0 - RAD + lx, Wn);
        int o = ly * PITCH + lx;
        arrs[o] = Xp[gy * Wn + gx];
        arrs[ASZ + o] = Gp[gy * Wn + gx];
    }
    __syncthreads();

    int x = t & 31, g = t >> 5, r0 = g * 4;
    float acc[5][4];
    ss_hbox2<false>(arrs, hs, t);
    __syncthreads();
    ss_vbox(hs, x, r0, acc[0]);
    ss_vbox(hs + HSZ, x, r0, acc[1]);
    __syncthreads();
    ss_hbox2<true>(arrs, hs, t);
    __syncthreads();
    ss_vbox(hs, x, r0, acc[2]);
    ss_vbox(hs + HSZ, x, r0, acc[3]);
    __syncthreads();
    if (t < 168) {
        int y = t >> 2, c = t & 3;
        const float* sx = arrs + y * PITCH + 8 * c;
        const float* sg = arrs + ASZ + y * PITCH + 8 * c;
        float* hd = hs + y * HP + 8 * c;
        float s = sx[0] * sg[0];
#pragma unroll
        for (int dx = 1; dx < K; ++dx) s += sx[dx] * sg[dx];
        hd[0] = s;
#pragma unroll
        for (int j = 1; j < 8; ++j) {
            s += sx[j + 10] * sg[j + 10] - sx[j - 1] * sg[j - 1];
            hd[j] = s;
        }
    }
    __syncthreads();
    ss_vbox(hs, x, r0, acc[4]);

    float m1[5][4];
#pragma unroll
    for (int p = 0; p < 5; ++p) {
        float h3[6];
#pragma unroll
        for (int j = 0; j < 6; ++j) {
            int bb = (r0 + 4 + j) * PITCH + (x + 4);
            float s = 0.f;
#pragma unroll
            for (int i = 0; i < 3; ++i) {
                float vx = arrs[bb + i], vg = arrs[ASZ + bb + i];
                float v = (p == 0) ? vx : (p == 1) ? vg : (p == 2) ? vx * vx
                          : (p == 3) ? vg * vg : vx * vg;
                s += v;
            }
            h3[j] = s;
        }
#pragma unroll
        for (int j = 0; j < 4; ++j)
            m1[p][j] = (h3[j] + h3[j + 1] + h3[j + 2]) * (1.f / 9.f);
    }

    float l1 = 0.f, l2 = 0.f;
    float outv[5][4];
#pragma unroll
    for (int j = 0; j < 4; ++j) {
        float mux = acc[0][j], mug = acc[1][j], mxx = acc[2][j], mgg = acc[3][j], mxy = acc[4][j];
        float sx2 = fmaxf(mxx - mux * mux, 0.f);
        float sg2 = fmaxf(mgg - mug * mug, 0.f);
        float sxy = mxy - mux * mug;
        float num = (2.f * mux * mug + C1C) * (2.f * sxy + C2C);
        float den = (mux * mux + mug * mug + C1C) * (sx2 + sg2 + C2C);
        float tr_ = fminf(fmaxf((num / (den + DEN_EPS) + 1.f) * 0.5f, 0.f), 1.f);

        float n0 = m1[0][j], n1 = m1[1][j], n2 = m1[2][j], n3 = m1[3][j], n4 = m1[4][j];
        float sx21 = fmaxf(n2 - n0 * n0, 0.f);
        float sg21 = fmaxf(n3 - n1 * n1, 0.f);
        float sxy1 = n4 - n0 * n1;
        float num1 = (2.f * n0 * n1 + C1C) * (2.f * sxy1 + C2C);
        float den1 = (n0 * n0 + n1 * n1 + C1C) * (sx21 + sg21 + C2C);
        float t1_ = fminf(fmaxf((num1 / (den1 + DEN_EPS) + 1.f) * 0.5f, 0.f), 1.f);

        float chig_ = sqrtf(sg21 + EPSC) * sqrtf(sg2 + EPSC);
        float nu_ = fmaxf(t1_ * tr_, 0.f);
        outv[0][j] = mug; outv[1][j] = sg2; outv[2][j] = tr_;
        outv[3][j] = chig_; outv[4][j] = nu_;
        l1 += 1.f / (chig_ + EPSC);
        l2 += 1.f / (nu_ + THETAC);
    }
#pragma unroll
    for (int j = 0; j < 4; ++j) {
        int gp = b * HW + (ty0 + r0 + j) * Wn + (tx0 + x);
        muG[gp] = outv[0][j];
        varGr[gp] = outv[1][j];
        taur[gp] = outv[2][j];
        chig[gp] = outv[3][j];
        nu[gp] = outv[4][j];
    }
    __syncthreads();
    red1[t] = l1; red2[t] = l2;
    __syncthreads();
    for (int s = 128; s > 0; s >>= 1) {
        if (t < s) { red1[t] += red1[t + s]; red2[t] += red2[t + s]; }
        __syncthreads();
    }
    if (t == 0) {
        ps1[b * NT + blockIdx.x] = red1[0];
        ps2[b * NT + blockIdx.x] = red2[0];
    }
}

// ---------------- K red ----------------
__global__ void __launch_bounds__(256) k_red(
        const float* __restrict__ psum, const float* __restrict__ pmin,
        const float* __restrict__ s1, const float* __restrict__ s2,
        float* __restrict__ sc) {
    __shared__ float a1[256], a2[256];
    int t = threadIdx.x;
    if (blockIdx.x < 4) {
        int b = blockIdx.x;
        a1[t] = psum[b * 256 + t];
        a2[t] = pmin[b * 256 + t];
        __syncthreads();
        for (int s = 128; s > 0; s >>= 1) {
            if (t < s) { a1[t] += a1[t + s]; a2[t] = fminf(a2[t], a2[t + s]); }
            __syncthreads();
        }
        if (t == 0) {
            float mu = a1[0] / (float)HW;
            sc[b] = mu;
            sc[4 + b] = fmaxf(mu - a2[0], EPSC);
        }
    } else {
        int b = blockIdx.x - 4;
        a1[t] = s1[b * 256 + t];
        a2[t] = s2[b * 256 + t];
        __syncthreads();
        for (int s = 128; s > 0; s >>= 1) {
            if (t < s) { a1[t] += a1[t + s]; a2[t] += a2[t + s]; }
            __syncthreads();
        }
        if (t == 0) {
            sc[8 + b] = a1[0] / (float)HW;
            sc[12 + b] = a2[0] / (float)HW;
        }
    }
}

// ---------------- K4: packed (P, D, muG) plane, 4-wide ----------------
__global__ void __launch_bounds__(256) k_pd(
        const float* __restrict__ chi, const float* __restrict__ chig,
        const float* __restrict__ nu, const float* __restrict__ taur,
        const float* __restrict__ vr, const float* __restrict__ muG,
        const float* __restrict__ sc, float4* __restrict__ PDM) {
    int i = blockIdx.x * 256 + threadIdx.x;
    int p0 = i * 4;
    int b = p0 >> 18;
    float mu = sc[b], eta = sc[4 + b], imc = sc[8 + b], imn = sc[12 + b];
    float4 c4 = ((const float4*)chi)[i];
    float4 cg4 = ((const float4*)chig)[i];
    float4 nu4 = ((const float4*)nu)[i];
    float4 tr4 = ((const float4*)taur)[i];
    float4 vr4 = ((const float4*)vr)[i];
    float4 mg4 = ((const float4*)muG)[i];
    float cc[4] = {c4.x, c4.y, c4.z, c4.w};
    float gg[4] = {cg4.x, cg4.y, cg4.z, cg4.w};
    float nn[4] = {nu4.x, nu4.y, nu4.z, nu4.w};
    float tt[4] = {tr4.x, tr4.y, tr4.z, tr4.w};
    float vv[4] = {vr4.x, vr4.y, vr4.z, vr4.w};
    float mm[4] = {mg4.x, mg4.y, mg4.z, mg4.w};
#pragma unroll
    for (int j = 0; j < 4; ++j) {
        float gamma = 1.f / (1.f + expf(-eta * (cc[j] - mu)));
        float GG = (gg[j] + EPSC) * imc;
        float w_e = 1.0f / (GG + EPSC);
        float GS = (nn[j] + THETAC) * imn;
        float w_s = gamma / (GS + EPSC);
        float P = w_e * gamma + w_s * tt[j];
        float D = vv[j] + EPSC + w_e + w_s + EPSC;
        PDM[p0 + j] = make_float4(P, D, mm[j], 0.f);
    }
}

// ---------------- K5: per-channel a,b (compact window, merged hbox, 2 barriers) ----------------
__global__ void __launch_bounds__(256) k_ab(
        const float* __restrict__ X, const float* __restrict__ G,
        const float4* __restrict__ PDM, unsigned int* __restrict__ AB) {
    __shared__ float s0[CS], s1[CS];     // X, X*G (42-wide window, pitch 43)
    __shared__ float h0[HSZ], h1[HSZ];
    int t = threadIdx.x;
    int pc = blockIdx.y, b = pc >> 4;
    int tile = swz_tile(blockIdx.x);
    int tx0 = (tile & 15) * TS, ty0 = (tile >> 4) * TS;
    int x = t & 31, wg = t >> 5, r0 = wg * 4;
    // prefetch epilogue operands
    const float4* Pp = PDM + (size_t)b * HW;
    int pbase = (ty0 + r0) * Wn + tx0 + x;
    float4 pdm[4];
#pragma unroll
    for (int j = 0; j < 4; ++j) pdm[j] = Pp[pbase + j * Wn];

    const float* Xp = X + (size_t)pc * HW;
    const float* Gp = G + (size_t)b * HW;
    bool interior = (tx0 >= 32 && tx0 <= 448 && ty0 >= 32 && ty0 <= 448);
    if (interior) {
        int base = (ty0 - 5) * Wn + (tx0 - 8);
        for (int u = t; u < HALO * 12; u += 256) {
            int ly = u / 12, k = u - ly * 12;
            int gi = base + ly * Wn + 4 * k;
            float4 xv = *(const float4*)(Xp + gi);
            float4 gv = *(const float4*)(Gp + gi);
            float xa[4] = {xv.x, xv.y, xv.z, xv.w};
            float ga[4] = {gv.x, gv.y, gv.z, gv.w};
            int o = ly * CP + 4 * k - 3;
#pragma unroll
            for (int i = 0; i < 4; ++i) {
                int wc = 4 * k + i - 3;
                if (wc >= 0 && wc < 42) {
                    s0[o + i] = xa[i];
                    s1[o + i] = xa[i] * ga[i];
                }
            }
        }
    } else {
        for (int u = t; u < HALO * HALO; u += 256) {
            int ly = u / HALO, l = u - ly * HALO;
            int gy = refl(ty0 - 5 + ly, Hn), gx = refl(tx0 - 5 + l, Wn);
            float xv = Xp[gy * Wn + gx], gv = Gp[gy * Wn + gx];
            s0[ly * CP + l] = xv;
            s1[ly * CP + l] = xv * gv;
        }
    }
    __syncthreads();

    // merged hbox: 336 tasks = 2 planes x 42 rows x 4 chunks (8-wide)
    for (int u = t; u < 336; u += 256) {
        int pl = u & 1, rem = u >> 1;
        int y = rem >> 2, c = rem & 3;
        const float* src = (pl ? s1 : s0) + y * CP + 8 * c;
        float* dst = (pl ? h1 : h0) + y * HP + 8 * c;
        float acc = src[0];
#pragma unroll
        for (int dx = 1; dx < K; ++dx) acc += src[dx];
        dst[0] = acc;
#pragma unroll
        for (int j = 1; j < 8; ++j) {
            acc += src[j + 10] - src[j - 1];
            dst[j] = acc;
        }
    }
    __syncthreads();

    float mx[4], mxg[4];
    vbox4(h0, x, r0, mx);
    vbox4(h1, x, r0, mxg);

    unsigned int* Ap = AB + (size_t)pc * HW;
#pragma unroll
    for (int j = 0; j < 4; ++j) {
        float a = (mxg[j] - pdm[j].z * mx[j] + pdm[j].x) / pdm[j].y;
        float bb = mx[j] - a * pdm[j].z;
        Ap[pbase + j * Wn] = bf16pack(a, bb);
    }
}

// ---------------- K6: out = box11(a)*G + box11(b) (packed window, 2 barriers) ----------------
__global__ void __launch_bounds__(256) k_out(
        const unsigned int* __restrict__ AB, const float* __restrict__ G,
        float* __restrict__ out) {
    __shared__ unsigned int su[CS];      // packed (a,b), 42-wide pitch 43
    __shared__ float h0[HSZ], h1[HSZ];
    int t = threadIdx.x;
    int pc = blockIdx.y, b = pc >> 4;
    int tile = swz_tile(blockIdx.x);
    int tx0 = (tile & 15) * TS, ty0 = (tile >> 4) * TS;
    int x = t & 31, wg = t >> 5, r0 = wg * 4;
    // prefetch G for epilogue
    const float* Gp = G + (size_t)b * HW;
    int pbase = (ty0 + r0) * Wn + tx0 + x;
    float gv[4];
#pragma unroll
    for (int j = 0; j < 4; ++j) gv[j] = Gp[pbase + j * Wn];

    const unsigned int* Ap = AB + (size_t)pc * HW;
    bool interior = (tx0 >= 32 && tx0 <= 448 && ty0 >= 32 && ty0 <= 448);
    if (interior) {
        int base = (ty0 - 5) * Wn + (tx0 - 8);
        for (int u = t; u < HALO * 12; u += 256) {
            int ly = u / 12, k = u - ly * 12;
            uint4 v = *(const uint4*)(Ap + base + ly * Wn + 4 * k);
            unsigned int va[4] = {v.x, v.y, v.z, v.w};
            int o = ly * CP + 4 * k - 3;
#pragma unroll
            for (int i = 0; i < 4; ++i) {
                int wc = 4 * k + i - 3;
                if (wc >= 0 && wc < 42) su[o + i] = va[i];
            }
        }
    } else {
        for (int u = t; u < HALO * HALO; u += 256) {
            int ly = u / HALO, l = u - ly * HALO;
            int gy = refl(ty0 - 5 + ly, Hn), gx = refl(tx0 - 5 + l, Wn);
            su[ly * CP + l] = Ap[gy * Wn + gx];
        }
    }
    __syncthreads();

    // merged hbox with branchless bf16 unpack: 336 tasks
    for (int u = t; u < 336; u += 256) {
        int pl = u & 1, rem = u >> 1;
        int y = rem >> 2, c = rem & 3;
        const unsigned int* src = su + y * CP + 8 * c;
        float* dst = (pl ? h1 : h0) + y * HP + 8 * c;
        unsigned int msk = pl ? 0xFFFF0000u : 0u;   // pl=1: hi; pl=0: lo (shift)
        int sh = pl ? 0 : 16;
        float acc = __uint_as_float((src[0] << sh) & (pl ? msk : 0xFFFF0000u));
        // simpler: recompute per tap
        acc = pl ? bfhi(src[0]) : bflo(src[0]);
#pragma unroll
        for (int dx = 1; dx < K; ++dx) acc += pl ? bfhi(src[dx]) : bflo(src[dx]);
        dst[0] = acc;
#pragma unroll
        for (int j = 1; j < 8; ++j) {
            acc += (pl ? bfhi(src[j + 10]) : bflo(src[j + 10]))
                 - (pl ? bfhi(src[j - 1]) : bflo(src[j - 1]));
            dst[j] = acc;
        }
        (void)msk; (void)sh;
    }
    __syncthreads();

    float ma[4], mb[4];
    vbox4(h0, x, r0, ma);
    vbox4(h1, x, r0, mb);

    float* op = out + (size_t)pc * HW;
#pragma unroll
    for (int j = 0; j < 4; ++j)
        op[pbase + j * Wn] = ma[j] * gv[j] + mb[j];
}

extern "C" void kernel_launch(void* const* d_in, const int* in_sizes, int n_in,
                              void* d_out, int out_size, void* d_ws, size_t ws_size,
                              hipStream_t stream) {
    const float* X = (const float*)d_in[0];
    const float* G = (const float*)d_in[1];
    float* out = (float*)d_out;
    float* ws = (float*)d_ws;

    float* Xs   = ws + 0 * (size_t)NP;
    float* chi  = ws + 1 * (size_t)NP;
    float* taur = ws + 2 * (size_t)NP;
    float* vr   = ws + 3 * (size_t)NP;
    float* muG  = ws + 4 * (size_t)NP;
    float* chig = ws + 5 * (size_t)NP;
    float* nu   = ws + 6 * (size_t)NP;
    float4* PDM = (float4*)(ws + 7 * (size_t)NP);            // 4*NP floats
    unsigned int* AB = (unsigned int*)(ws + 11 * (size_t)NP); // NX uints
    float* psum = ws + 43 * (size_t)NP;
    float* pmin = psum + 1024;
    float* ps1  = pmin + 1024;
    float* ps2  = ps1 + 1024;
    float* sc   = ps2 + 1024;   // 16 scalars

    dim3 blk(256);
    k_xschi<<<2048, blk, 0, stream>>>(X, G, Xs, chi, psum, pmin);

    dim3 gplane(NT, Bn);
    k_ssim<<<gplane, blk, 0, stream>>>(Xs, G, muG, vr, taur, chig, nu, ps1, ps2);
    k_red<<<8, blk, 0, stream>>>(psum, pmin, ps1, ps2, sc);
    k_pd<<<(NP / 4) / 256, blk, 0, stream>>>(chi, chig, nu, taur, vr, muG, sc, PDM);

    dim3 gchan(NT, Bn * Cn);
    k_ab<<<gchan, blk, 0, stream>>>(X, G, PDM, AB);
    k_out<<<gchan, blk, 0, stream>>>(AB, G, out);
}

// Round 9
// 126.697 us; speedup vs baseline: 1.0907x; 1.0551x over previous
//
#include <hip/hip_runtime.h>
#include <math.h>

#define EPSC 1e-6f
#define THETAC 1e-3f
#define C1C 1e-4f
#define C2C 9e-4f
#define DEN_EPS 1e-12f

constexpr int Bn = 4, Cn = 16, Hn = 512, Wn = 512;
constexpr int HW = Hn * Wn;          // 262144 = 2^18
constexpr int NP = Bn * HW;          // 1048576
constexpr int TS = 32, RAD = 5, K = 11;
constexpr int HALO = TS + 2 * RAD;   // 42
constexpr int PITCH = 43;            // k_ssim halo pitch
constexpr int HP = 33;               // horizontal-sum pitch (linear, conflict-free)
constexpr int ASZ = HALO * PITCH;    // 1806
constexpr int HSZ = HALO * HP;       // 1386
constexpr int tiles_x = Wn / TS;     // 16
constexpr int NT = tiles_x * (Hn / TS); // 256

// channel-pass geometry: 48-wide aligned window, pitch 49
constexpr int PW = 49;
constexpr int SSZ = HALO * PW;       // 2058

__device__ __forceinline__ int refl(int i, int n) {
    if (i < 0) i = -i;
    if (i >= n) i = 2 * n - 2 - i;
    return i;
}

__device__ __forceinline__ int swz_tile(int x) { return (x & 7) * (NT / 8) + (x >> 3); }

__device__ __forceinline__ unsigned int bf16pack(float a, float b) {
    unsigned int ua = __float_as_uint(a), ub = __float_as_uint(b);
    ua += 0x7FFFu + ((ua >> 16) & 1u);
    ub += 0x7FFFu + ((ub >> 16) & 1u);
    return (ua >> 16) | (ub & 0xFFFF0000u);
}
__device__ __forceinline__ float bflo(unsigned int v) { return __uint_as_float(v << 16); }
__device__ __forceinline__ float bfhi(unsigned int v) { return __uint_as_float(v & 0xFFFF0000u); }

// vbox4 over linear pitch-33 h
__device__ __forceinline__ void vbox4(const float* h, int x, int r0, float m[4]) {
    const float inv = 1.f / 121.f;
    const float* hb = h + r0 * HP + x;
    float s = hb[0];
#pragma unroll
    for (int dy = 1; dy < K; ++dy) s += hb[dy * HP];
    m[0] = s * inv;
#pragma unroll
    for (int j = 1; j < 4; ++j) {
        s += hb[(j + 10) * HP] - hb[(j - 1) * HP];
        m[j] = s * inv;
    }
}

// ---------------- K1: merged Xs (channel mean) + chi (+partial reductions) ----------------
__global__ void __launch_bounds__(256) k_xschi(
        const float* __restrict__ X, const float* __restrict__ G,
        float* __restrict__ Xs, float* __restrict__ chi,
        float* __restrict__ psum, float* __restrict__ pmin) {
    int t = threadIdx.x;
    if (blockIdx.x < 1024) {
        constexpr int HW4 = HW / 4;
        int i = blockIdx.x * 256 + t;
        int b = i / HW4, off = i - b * HW4;
        const float4* xp = (const float4*)(X + (size_t)b * Cn * HW) + off;
        float4 s = make_float4(0.f, 0.f, 0.f, 0.f);
#pragma unroll
        for (int c = 0; c < Cn; ++c) {
            float4 v = xp[(size_t)c * HW4];
            s.x += v.x; s.y += v.y; s.z += v.z; s.w += v.w;
        }
        const float sc = 1.0f / Cn;
        s.x *= sc; s.y *= sc; s.z *= sc; s.w *= sc;
        ((float4*)Xs)[i] = s;
        return;
    }
    __shared__ float ssum[256], smin[256];
    int bid = blockIdx.x - 1024;
    int base = bid * 1024;
    float ls = 0.f, lm = 1e30f;
#pragma unroll
    for (int k = 0; k < 4; ++k) {
        int p = base + t + k * 256;
        int off = p & (HW - 1);
        int y = off / Wn, x = off & (Wn - 1);
        float g = G[p];
        float gx = (x < Wn - 1) ? G[p + 1] - g : 0.f;
        float gy = (y < Hn - 1) ? G[p + Wn] - g : 0.f;
        float c = sqrtf(gx * gx + gy * gy + EPSC);
        chi[p] = c;
        ls += c;
        lm = fminf(lm, c);
    }
    ssum[t] = ls; smin[t] = lm;
    __syncthreads();
    for (int s = 128; s > 0; s >>= 1) {
        if (t < s) { ssum[t] += ssum[t + s]; smin[t] = fminf(smin[t], smin[t + s]); }
        __syncthreads();
    }
    if (t == 0) { psum[bid] = ssum[0]; pmin[bid] = smin[0]; }
}

// k_ssim helpers
template <bool SQ>
__device__ __forceinline__ void ss_hbox2(const float* arrs, float* hs, int t) {
    if (t < 168) {
        int pl = t / 84, rem = t - pl * 84;
        int y = rem >> 1, xh = (rem & 1) << 4;
        const float* src = arrs + pl * ASZ + y * PITCH + xh;
        float* hd = hs + pl * HSZ + y * HP + xh;
        float v = src[0];
        float s = SQ ? v * v : v;
#pragma unroll
        for (int dx = 1; dx < K; ++dx) { float u = src[dx]; s += SQ ? u * u : u; }
        hd[0] = s;
#pragma unroll
        for (int j = 1; j < 16; ++j) {
            float un = src[j + 10], uo = src[j - 1];
            s += (SQ ? un * un : un) - (SQ ? uo * uo : uo);
            hd[j] = s;
        }
    }
}

__device__ __forceinline__ void ss_vbox(const float* hs, int x, int r0, float m[4]) {
    const float inv_area = 1.f / (float)(K * K);
    const float* hb = hs + r0 * HP + x;
    float s = hb[0];
#pragma unroll
    for (int dy = 1; dy < K; ++dy) s += hb[dy * HP];
    m[0] = s * inv_area;
#pragma unroll
    for (int j = 1; j < 4; ++j) {
        s += hb[(j + 10) * HP] - hb[(j - 1) * HP];
        m[j] = s * inv_area;
    }
}

// ---------------- K3: merged ssim r=5 & r=1 + plane outputs + reductions ----------------
__global__ void __launch_bounds__(256) k_ssim(
        const float* __restrict__ Xs, const float* __restrict__ G,
        float* __restrict__ muG, float* __restrict__ varGr, float* __restrict__ taur,
        float* __restrict__ chig, float* __restrict__ nu,
        float* __restrict__ ps1, float* __restrict__ ps2) {
    __shared__ float arrs[2 * ASZ];
    __shared__ float hs[2 * HSZ];
    float* red1 = hs;
    float* red2 = hs + HSZ;
    int t = threadIdx.x;
    int b = blockIdx.y;
    int tile = swz_tile(blockIdx.x);
    int tx0 = (tile % tiles_x) * TS, ty0 = (tile / tiles_x) * TS;
    const float* Xp = Xs + (size_t)b * HW;
    const float* Gp = G + (size_t)b * HW;
    for (int i = t; i < HALO * HALO; i += 256) {
        int ly = i / HALO, lx = i - ly * HALO;
        int gy = refl(ty0 - RAD + ly, Hn), gx = refl(tx0 - RAD + lx, Wn);
        int o = ly * PITCH + lx;
        arrs[o] = Xp[gy * Wn + gx];
        arrs[ASZ + o] = Gp[gy * Wn + gx];
    }
    __syncthreads();

    int x = t & 31, g = t >> 5, r0 = g * 4;
    float acc[5][4];
    ss_hbox2<false>(arrs, hs, t);
    __syncthreads();
    ss_vbox(hs, x, r0, acc[0]);
    ss_vbox(hs + HSZ, x, r0, acc[1]);
    __syncthreads();
    ss_hbox2<true>(arrs, hs, t);
    __syncthreads();
    ss_vbox(hs, x, r0, acc[2]);
    ss_vbox(hs + HSZ, x, r0, acc[3]);
    __syncthreads();
    if (t < 168) {
        int y = t >> 2, c = t & 3;
        const float* sx = arrs + y * PITCH + 8 * c;
        const float* sg = arrs + ASZ + y * PITCH + 8 * c;
        float* hd = hs + y * HP + 8 * c;
        float s = sx[0] * sg[0];
#pragma unroll
        for (int dx = 1; dx < K; ++dx) s += sx[dx] * sg[dx];
        hd[0] = s;
#pragma unroll
        for (int j = 1; j < 8; ++j) {
            s += sx[j + 10] * sg[j + 10] - sx[j - 1] * sg[j - 1];
            hd[j] = s;
        }
    }
    __syncthreads();
    ss_vbox(hs, x, r0, acc[4]);

    float m1[5][4];
#pragma unroll
    for (int p = 0; p < 5; ++p) {
        float h3[6];
#pragma unroll
        for (int j = 0; j < 6; ++j) {
            int bb = (r0 + 4 + j) * PITCH + (x + 4);
            float s = 0.f;
#pragma unroll
            for (int i = 0; i < 3; ++i) {
                float vx = arrs[bb + i], vg = arrs[ASZ + bb + i];
                float v = (p == 0) ? vx : (p == 1) ? vg : (p == 2) ? vx * vx
                          : (p == 3) ? vg * vg : vx * vg;
                s += v;
            }
            h3[j] = s;
        }
#pragma unroll
        for (int j = 0; j < 4; ++j)
            m1[p][j] = (h3[j] + h3[j + 1] + h3[j + 2]) * (1.f / 9.f);
    }

    float l1 = 0.f, l2 = 0.f;
    float outv[5][4];
#pragma unroll
    for (int j = 0; j < 4; ++j) {
        float mux = acc[0][j], mug = acc[1][j], mxx = acc[2][j], mgg = acc[3][j], mxy = acc[4][j];
        float sx2 = fmaxf(mxx - mux * mux, 0.f);
        float sg2 = fmaxf(mgg - mug * mug, 0.f);
        float sxy = mxy - mux * mug;
        float num = (2.f * mux * mug + C1C) * (2.f * sxy + C2C);
        float den = (mux * mux + mug * mug + C1C) * (sx2 + sg2 + C2C);
        float tr_ = fminf(fmaxf((num / (den + DEN_EPS) + 1.f) * 0.5f, 0.f), 1.f);

        float n0 = m1[0][j], n1 = m1[1][j], n2 = m1[2][j], n3 = m1[3][j], n4 = m1[4][j];
        float sx21 = fmaxf(n2 - n0 * n0, 0.f);
        float sg21 = fmaxf(n3 - n1 * n1, 0.f);
        float sxy1 = n4 - n0 * n1;
        float num1 = (2.f * n0 * n1 + C1C) * (2.f * sxy1 + C2C);
        float den1 = (n0 * n0 + n1 * n1 + C1C) * (sx21 + sg21 + C2C);
        float t1_ = fminf(fmaxf((num1 / (den1 + DEN_EPS) + 1.f) * 0.5f, 0.f), 1.f);

        float chig_ = sqrtf(sg21 + EPSC) * sqrtf(sg2 + EPSC);
        float nu_ = fmaxf(t1_ * tr_, 0.f);
        outv[0][j] = mug; outv[1][j] = sg2; outv[2][j] = tr_;
        outv[3][j] = chig_; outv[4][j] = nu_;
        l1 += 1.f / (chig_ + EPSC);
        l2 += 1.f / (nu_ + THETAC);
    }
#pragma unroll
    for (int j = 0; j < 4; ++j) {
        int gp = b * HW + (ty0 + r0 + j) * Wn + (tx0 + x);
        muG[gp] = outv[0][j];
        varGr[gp] = outv[1][j];
        taur[gp] = outv[2][j];
        chig[gp] = outv[3][j];
        nu[gp] = outv[4][j];
    }
    __syncthreads();
    red1[t] = l1; red2[t] = l2;
    __syncthreads();
    for (int s = 128; s > 0; s >>= 1) {
        if (t < s) { red1[t] += red1[t + s]; red2[t] += red2[t + s]; }
        __syncthreads();
    }
    if (t == 0) {
        ps1[b * NT + blockIdx.x] = red1[0];
        ps2[b * NT + blockIdx.x] = red2[0];
    }
}

// ---------------- K red ----------------
__global__ void __launch_bounds__(256) k_red(
        const float* __restrict__ psum, const float* __restrict__ pmin,
        const float* __restrict__ s1, const float* __restrict__ s2,
        float* __restrict__ sc) {
    __shared__ float a1[256], a2[256];
    int t = threadIdx.x;
    if (blockIdx.x < 4) {
        int b = blockIdx.x;
        a1[t] = psum[b * 256 + t];
        a2[t] = pmin[b * 256 + t];
        __syncthreads();
        for (int s = 128; s > 0; s >>= 1) {
            if (t < s) { a1[t] += a1[t + s]; a2[t] = fminf(a2[t], a2[t + s]); }
            __syncthreads();
        }
        if (t == 0) {
            float mu = a1[0] / (float)HW;
            sc[b] = mu;
            sc[4 + b] = fmaxf(mu - a2[0], EPSC);
        }
    } else {
        int b = blockIdx.x - 4;
        a1[t] = s1[b * 256 + t];
        a2[t] = s2[b * 256 + t];
        __syncthreads();
        for (int s = 128; s > 0; s >>= 1) {
            if (t < s) { a1[t] += a1[t + s]; a2[t] += a2[t + s]; }
            __syncthreads();
        }
        if (t == 0) {
            sc[8 + b] = a1[0] / (float)HW;
            sc[12 + b] = a2[0] / (float)HW;
        }
    }
}

// ---------------- K4: packed (P, invD, muG) plane, 4-wide ----------------
__global__ void __launch_bounds__(256) k_pd(
        const float* __restrict__ chi, const float* __restrict__ chig,
        const float* __restrict__ nu, const float* __restrict__ taur,
        const float* __restrict__ vr, const float* __restrict__ muG,
        const float* __restrict__ sc, float4* __restrict__ PDM) {
    int i = blockIdx.x * 256 + threadIdx.x;
    int p0 = i * 4;
    int b = p0 >> 18;
    float mu = sc[b], eta = sc[4 + b], imc = sc[8 + b], imn = sc[12 + b];
    float4 c4 = ((const float4*)chi)[i];
    float4 cg4 = ((const float4*)chig)[i];
    float4 nu4 = ((const float4*)nu)[i];
    float4 tr4 = ((const float4*)taur)[i];
    float4 vr4 = ((const float4*)vr)[i];
    float4 mg4 = ((const float4*)muG)[i];
    float cc[4] = {c4.x, c4.y, c4.z, c4.w};
    float gg[4] = {cg4.x, cg4.y, cg4.z, cg4.w};
    float nn[4] = {nu4.x, nu4.y, nu4.z, nu4.w};
    float tt[4] = {tr4.x, tr4.y, tr4.z, tr4.w};
    float vv[4] = {vr4.x, vr4.y, vr4.z, vr4.w};
    float mm[4] = {mg4.x, mg4.y, mg4.z, mg4.w};
#pragma unroll
    for (int j = 0; j < 4; ++j) {
        float gamma = 1.f / (1.f + expf(-eta * (cc[j] - mu)));
        float GG = (gg[j] + EPSC) * imc;
        float w_e = 1.0f / (GG + EPSC);
        float GS = (nn[j] + THETAC) * imn;
        float w_s = gamma / (GS + EPSC);
        float P = w_e * gamma + w_s * tt[j];
        float D = vv[j] + EPSC + w_e + w_s + EPSC;
        PDM[p0 + j] = make_float4(P, 1.0f / D, mm[j], 0.f);
    }
}

// ---------------- K5: per-channel a,b (merged hbox, 2 barriers, invD) ----------------
__global__ void __launch_bounds__(256) k_ab(
        const float* __restrict__ X, const float* __restrict__ G,
        const float4* __restrict__ PDM, unsigned int* __restrict__ AB) {
    __shared__ float s0[SSZ], s1[SSZ];   // X, X*G (48-wide window, pitch 49)
    __shared__ float h0[HSZ], h1[HSZ];
    int t = threadIdx.x;
    int pc = blockIdx.y, b = pc >> 4;
    int tile = swz_tile(blockIdx.x);
    int tx0 = (tile & 15) * TS, ty0 = (tile >> 4) * TS;
    int x = t & 31, wg = t >> 5, r0 = wg * 4;
    // prefetch epilogue operands (latency hides under staging/hbox)
    const float4* Pp = PDM + (size_t)b * HW;
    int pbase = (ty0 + r0) * Wn + tx0 + x;
    float4 pdm[4];
#pragma unroll
    for (int j = 0; j < 4; ++j) pdm[j] = Pp[pbase + j * Wn];

    const float* Xp = X + (size_t)pc * HW;
    const float* Gp = G + (size_t)b * HW;
    bool interior = (tx0 >= 32 && tx0 <= 448 && ty0 >= 32 && ty0 <= 448);
    if (interior) {
        int base = (ty0 - 5) * Wn + (tx0 - 8);
        for (int u = t; u < HALO * 12; u += 256) {     // 504 float4 units
            int ly = u / 12, k = u - ly * 12;
            int gi = base + ly * Wn + 4 * k;
            float4 xv = *(const float4*)(Xp + gi);
            float4 gv = *(const float4*)(Gp + gi);
            int o = ly * PW + 4 * k;
            s0[o] = xv.x; s0[o + 1] = xv.y; s0[o + 2] = xv.z; s0[o + 3] = xv.w;
            s1[o] = xv.x * gv.x; s1[o + 1] = xv.y * gv.y;
            s1[o + 2] = xv.z * gv.z; s1[o + 3] = xv.w * gv.w;
        }
    } else {
        for (int u = t; u < HALO * 48; u += 256) {
            int ly = u / 48, l = u - ly * 48;
            int gy = refl(ty0 - 5 + ly, Hn), gx = refl(tx0 - 8 + l, Wn);
            float xv = Xp[gy * Wn + gx], gv = Gp[gy * Wn + gx];
            s0[ly * PW + l] = xv;
            s1[ly * PW + l] = xv * gv;
        }
    }
    __syncthreads();

    // merged hbox: 168 tasks, each produces 8 h-values for BOTH planes
    if (t < 168) {
        int y = t >> 2, c = t & 3;
        const float* sx = s0 + y * PW + 8 * c + 3;
        const float* sz = s1 + y * PW + 8 * c + 3;
        float* d0 = h0 + y * HP + 8 * c;
        float* d1 = h1 + y * HP + 8 * c;
        float a0 = sx[0], a1 = sz[0];
#pragma unroll
        for (int dx = 1; dx < K; ++dx) { a0 += sx[dx]; a1 += sz[dx]; }
        d0[0] = a0; d1[0] = a1;
#pragma unroll
        for (int j = 1; j < 8; ++j) {
            a0 += sx[j + 10] - sx[j - 1];
            a1 += sz[j + 10] - sz[j - 1];
            d0[j] = a0; d1[j] = a1;
        }
    }
    __syncthreads();

    float mx[4], mxg[4];
    vbox4(h0, x, r0, mx);
    vbox4(h1, x, r0, mxg);

    unsigned int* Ap = AB + (size_t)pc * HW;
#pragma unroll
    for (int j = 0; j < 4; ++j) {
        float a = (mxg[j] - pdm[j].z * mx[j] + pdm[j].x) * pdm[j].y;  // *invD
        float bb = mx[j] - a * pdm[j].z;
        Ap[pbase + j * Wn] = bf16pack(a, bb);
    }
}

// ---------------- K6: out = box11(a)*G + box11(b) (packed LDS window, 2 barriers) ----------------
__global__ void __launch_bounds__(256) k_out(
        const unsigned int* __restrict__ AB, const float* __restrict__ G,
        float* __restrict__ out) {
    __shared__ unsigned int su[SSZ];     // packed (a,b), pitch 49
    __shared__ float h0[HSZ], h1[HSZ];
    int t = threadIdx.x;
    int pc = blockIdx.y, b = pc >> 4;
    int tile = swz_tile(blockIdx.x);
    int tx0 = (tile & 15) * TS, ty0 = (tile >> 4) * TS;
    int x = t & 31, wg = t >> 5, r0 = wg * 4;
    // prefetch G for epilogue
    const float* Gp = G + (size_t)b * HW;
    int pbase = (ty0 + r0) * Wn + tx0 + x;
    float gv[4];
#pragma unroll
    for (int j = 0; j < 4; ++j) gv[j] = Gp[pbase + j * Wn];

    const unsigned int* Ap = AB + (size_t)pc * HW;
    bool interior = (tx0 >= 32 && tx0 <= 448 && ty0 >= 32 && ty0 <= 448);
    if (interior) {
        int base = (ty0 - 5) * Wn + (tx0 - 8);
        for (int u = t; u < HALO * 12; u += 256) {     // 504 uint4 units
            int ly = u / 12, k = u - ly * 12;
            uint4 v = *(const uint4*)(Ap + base + ly * Wn + 4 * k);
            int o = ly * PW + 4 * k;
            su[o] = v.x; su[o + 1] = v.y; su[o + 2] = v.z; su[o + 3] = v.w;
        }
    } else {
        for (int u = t; u < HALO * 48; u += 256) {
            int ly = u / 48, l = u - ly * 48;
            int gy = refl(ty0 - 5 + ly, Hn), gx = refl(tx0 - 8 + l, Wn);
            su[ly * PW + l] = Ap[gy * Wn + gx];
        }
    }
    __syncthreads();

    // merged hbox with bf16 unpack at tap: 168 tasks, both planes per read
    if (t < 168) {
        int y = t >> 2, c = t & 3;
        const unsigned int* src = su + y * PW + 8 * c + 3;
        float* d0 = h0 + y * HP + 8 * c;
        float* d1 = h1 + y * HP + 8 * c;
        unsigned int u0 = src[0];
        float a0 = bflo(u0), a1 = bfhi(u0);
#pragma unroll
        for (int dx = 1; dx < K; ++dx) {
            unsigned int u = src[dx];
            a0 += bflo(u); a1 += bfhi(u);
        }
        d0[0] = a0; d1[0] = a1;
#pragma unroll
        for (int j = 1; j < 8; ++j) {
            unsigned int un = src[j + 10], uo = src[j - 1];
            a0 += bflo(un) - bflo(uo);
            a1 += bfhi(un) - bfhi(uo);
            d0[j] = a0; d1[j] = a1;
        }
    }
    __syncthreads();

    float ma[4], mb[4];
    vbox4(h0, x, r0, ma);
    vbox4(h1, x, r0, mb);

    float* op = out + (size_t)pc * HW;
#pragma unroll
    for (int j = 0; j < 4; ++j)
        op[pbase + j * Wn] = ma[j] * gv[j] + mb[j];
}

extern "C" void kernel_launch(void* const* d_in, const int* in_sizes, int n_in,
                              void* d_out, int out_size, void* d_ws, size_t ws_size,
                              hipStream_t stream) {
    const float* X = (const float*)d_in[0];
    const float* G = (const float*)d_in[1];
    float* out = (float*)d_out;
    float* ws = (float*)d_ws;

    float* Xs   = ws + 0 * (size_t)NP;
    float* chi  = ws + 1 * (size_t)NP;
    float* taur = ws + 2 * (size_t)NP;
    float* vr   = ws + 3 * (size_t)NP;
    float* muG  = ws + 4 * (size_t)NP;
    float* chig = ws + 5 * (size_t)NP;
    float* nu   = ws + 6 * (size_t)NP;
    float4* PDM = (float4*)(ws + 7 * (size_t)NP);            // 4*NP floats
    unsigned int* AB = (unsigned int*)(ws + 11 * (size_t)NP); // NX uints
    float* psum = ws + 43 * (size_t)NP;
    float* pmin = psum + 1024;
    float* ps1  = pmin + 1024;
    float* ps2  = ps1 + 1024;
    float* sc   = ps2 + 1024;   // 16 scalars

    dim3 blk(256);
    k_xschi<<<2048, blk, 0, stream>>>(X, G, Xs, chi, psum, pmin);

    dim3 gplane(NT, Bn);
    k_ssim<<<gplane, blk, 0, stream>>>(Xs, G, muG, vr, taur, chig, nu, ps1, ps2);
    k_red<<<8, blk, 0, stream>>>(psum, pmin, ps1, ps2, sc);
    k_pd<<<(NP / 4) / 256, blk, 0, stream>>>(chi, chig, nu, taur, vr, muG, sc, PDM);

    dim3 gchan(NT, Bn * Cn);
    k_ab<<<gchan, blk, 0, stream>>>(X, G, PDM, AB);
    k_out<<<gchan, blk, 0, stream>>>(AB, G, out);
}

// Round 10
// 111.295 us; speedup vs baseline: 1.2416x; 1.1384x over previous
//
#include <hip/hip_runtime.h>
#include <math.h>

#define EPSC 1e-6f
#define THETAC 1e-3f
#define C1C 1e-4f
#define C2C 9e-4f
#define DEN_EPS 1e-12f

constexpr int Bn = 4, Cn = 16, Hn = 512, Wn = 512;
constexpr int HW = Hn * Wn;          // 262144 = 2^18
constexpr int NP = Bn * HW;          // 1048576
constexpr int TS = 32, RAD = 5, K = 11;
constexpr int HALO = TS + 2 * RAD;   // 42
constexpr int HP = 33;               // horizontal-sum pitch (linear, conflict-free)
constexpr int HSZ = HALO * HP;       // 1386
constexpr int tiles_x = Wn / TS;     // 16
constexpr int NT = tiles_x * (Hn / TS); // 256

// 48-wide aligned window, pitch 49 (all tiled kernels)
constexpr int PW = 49;
constexpr int SSZ = HALO * PW;       // 2058

__device__ __forceinline__ int refl(int i, int n) {
    if (i < 0) i = -i;
    if (i >= n) i = 2 * n - 2 - i;
    return i;
}

__device__ __forceinline__ int swz_tile(int x) { return (x & 7) * (NT / 8) + (x >> 3); }

__device__ __forceinline__ unsigned int bf16pack(float a, float b) {
    unsigned int ua = __float_as_uint(a), ub = __float_as_uint(b);
    ua += 0x7FFFu + ((ua >> 16) & 1u);
    ub += 0x7FFFu + ((ub >> 16) & 1u);
    return (ua >> 16) | (ub & 0xFFFF0000u);
}
__device__ __forceinline__ float bflo(unsigned int v) { return __uint_as_float(v << 16); }
__device__ __forceinline__ float bfhi(unsigned int v) { return __uint_as_float(v & 0xFFFF0000u); }

// hbox 8-wide chunks into linear pitch-33 h: 168 threads; src window pitch 49, offset +3
__device__ __forceinline__ void hboxp(const float* s, float* h, int t) {
    if (t < 168) {
        int y = t >> 2, c = t & 3;
        const float* src = s + y * PW + 8 * c + 3;
        float* dst = h + y * HP + 8 * c;
        float acc = src[0];
#pragma unroll
        for (int dx = 1; dx < K; ++dx) acc += src[dx];
        dst[0] = acc;
#pragma unroll
        for (int j = 1; j < 8; ++j) {
            acc += src[j + 10] - src[j - 1];
            dst[j] = acc;
        }
    }
}

// vbox4 over linear pitch-33 h
__device__ __forceinline__ void vbox4(const float* h, int x, int r0, float m[4]) {
    const float inv = 1.f / 121.f;
    const float* hb = h + r0 * HP + x;
    float s = hb[0];
#pragma unroll
    for (int dy = 1; dy < K; ++dy) s += hb[dy * HP];
    m[0] = s * inv;
#pragma unroll
    for (int j = 1; j < 4; ++j) {
        s += hb[(j + 10) * HP] - hb[(j - 1) * HP];
        m[j] = s * inv;
    }
}

// ---------------- K1: merged Xs (channel mean) + chi (+partial reductions) ----------------
__global__ void __launch_bounds__(256) k_xschi(
        const float* __restrict__ X, const float* __restrict__ G,
        float* __restrict__ Xs, float* __restrict__ chi,
        float* __restrict__ psum, float* __restrict__ pmin) {
    int t = threadIdx.x;
    if (blockIdx.x < 1024) {
        constexpr int HW4 = HW / 4;
        int i = blockIdx.x * 256 + t;
        int b = i / HW4, off = i - b * HW4;
        const float4* xp = (const float4*)(X + (size_t)b * Cn * HW) + off;
        float4 s = make_float4(0.f, 0.f, 0.f, 0.f);
#pragma unroll
        for (int c = 0; c < Cn; ++c) {
            float4 v = xp[(size_t)c * HW4];
            s.x += v.x; s.y += v.y; s.z += v.z; s.w += v.w;
        }
        const float sc = 1.0f / Cn;
        s.x *= sc; s.y *= sc; s.z *= sc; s.w *= sc;
        ((float4*)Xs)[i] = s;
        return;
    }
    __shared__ float ssum[256], smin[256];
    int bid = blockIdx.x - 1024;
    int base = bid * 1024;
    float ls = 0.f, lm = 1e30f;
#pragma unroll
    for (int k = 0; k < 4; ++k) {
        int p = base + t + k * 256;
        int off = p & (HW - 1);
        int y = off / Wn, x = off & (Wn - 1);
        float g = G[p];
        float gx = (x < Wn - 1) ? G[p + 1] - g : 0.f;
        float gy = (y < Hn - 1) ? G[p + Wn] - g : 0.f;
        float c = sqrtf(gx * gx + gy * gy + EPSC);
        chi[p] = c;
        ls += c;
        lm = fminf(lm, c);
    }
    ssum[t] = ls; smin[t] = lm;
    __syncthreads();
    for (int s = 128; s > 0; s >>= 1) {
        if (t < s) { ssum[t] += ssum[t + s]; smin[t] = fminf(smin[t], smin[t + s]); }
        __syncthreads();
    }
    if (t == 0) { psum[bid] = ssum[0]; pmin[bid] = smin[0]; }
}

// k_ssim hbox over 2 planes at pitch 49 (+3 offset), optionally squared
template <bool SQ>
__device__ __forceinline__ void ss_hbox2(const float* arrs, float* hs, int t) {
    if (t < 168) {
        int pl = t / 84, rem = t - pl * 84;
        int y = rem >> 1, xh = (rem & 1) << 4;
        const float* src = arrs + pl * SSZ + y * PW + xh + 3;
        float* hd = hs + pl * HSZ + y * HP + xh;
        float v = src[0];
        float s = SQ ? v * v : v;
#pragma unroll
        for (int dx = 1; dx < K; ++dx) { float u = src[dx]; s += SQ ? u * u : u; }
        hd[0] = s;
#pragma unroll
        for (int j = 1; j < 16; ++j) {
            float un = src[j + 10], uo = src[j - 1];
            s += (SQ ? un * un : un) - (SQ ? uo * uo : uo);
            hd[j] = s;
        }
    }
}

__device__ __forceinline__ void ss_vbox(const float* hs, int x, int r0, float m[4]) {
    const float inv_area = 1.f / (float)(K * K);
    const float* hb = hs + r0 * HP + x;
    float s = hb[0];
#pragma unroll
    for (int dy = 1; dy < K; ++dy) s += hb[dy * HP];
    m[0] = s * inv_area;
#pragma unroll
    for (int j = 1; j < 4; ++j) {
        s += hb[(j + 10) * HP] - hb[(j - 1) * HP];
        m[j] = s * inv_area;
    }
}

// ---------------- K3: merged ssim r=5 & r=1 + plane outputs + reductions ----------------
__global__ void __launch_bounds__(256) k_ssim(
        const float* __restrict__ Xs, const float* __restrict__ G,
        float* __restrict__ muG, float* __restrict__ varGr, float* __restrict__ taur,
        float* __restrict__ chig, float* __restrict__ nu,
        float* __restrict__ ps1, float* __restrict__ ps2) {
    __shared__ float arrs[2 * SSZ];   // x, g windows (pitch 49, 48-wide aligned)
    __shared__ float hs[2 * HSZ];
    float* red1 = hs;
    float* red2 = hs + HSZ;
    int t = threadIdx.x;
    int b = blockIdx.y;
    int tile = swz_tile(blockIdx.x);
    int tx0 = (tile % tiles_x) * TS, ty0 = (tile / tiles_x) * TS;
    const float* Xp = Xs + (size_t)b * HW;
    const float* Gp = G + (size_t)b * HW;
    // vectorized staging with per-chunk validity
    for (int u = t; u < HALO * 12; u += 256) {
        int ly = u / 12, k = u - ly * 12;
        int gy = refl(ty0 - 5 + ly, Hn);
        int col = tx0 - 8 + 4 * k;
        int o = ly * PW + 4 * k;
        if (col >= 0 && col <= Wn - 4) {
            float4 xv = *(const float4*)(Xp + gy * Wn + col);
            float4 gv = *(const float4*)(Gp + gy * Wn + col);
            arrs[o] = xv.x; arrs[o + 1] = xv.y; arrs[o + 2] = xv.z; arrs[o + 3] = xv.w;
            arrs[SSZ + o] = gv.x; arrs[SSZ + o + 1] = gv.y;
            arrs[SSZ + o + 2] = gv.z; arrs[SSZ + o + 3] = gv.w;
        } else {
#pragma unroll
            for (int i = 0; i < 4; ++i) {
                int gx = refl(col + i, Wn);
                arrs[o + i] = Xp[gy * Wn + gx];
                arrs[SSZ + o + i] = Gp[gy * Wn + gx];
            }
        }
    }
    __syncthreads();

    int x = t & 31, g = t >> 5, r0 = g * 4;
    float acc[5][4];
    ss_hbox2<false>(arrs, hs, t);
    __syncthreads();
    ss_vbox(hs, x, r0, acc[0]);
    ss_vbox(hs + HSZ, x, r0, acc[1]);
    __syncthreads();
    ss_hbox2<true>(arrs, hs, t);
    __syncthreads();
    ss_vbox(hs, x, r0, acc[2]);
    ss_vbox(hs + HSZ, x, r0, acc[3]);
    __syncthreads();
    if (t < 168) {   // x*g plane, 8-wide chunks
        int y = t >> 2, c = t & 3;
        const float* sx = arrs + y * PW + 8 * c + 3;
        const float* sg = arrs + SSZ + y * PW + 8 * c + 3;
        float* hd = hs + y * HP + 8 * c;
        float s = sx[0] * sg[0];
#pragma unroll
        for (int dx = 1; dx < K; ++dx) s += sx[dx] * sg[dx];
        hd[0] = s;
#pragma unroll
        for (int j = 1; j < 8; ++j) {
            s += sx[j + 10] * sg[j + 10] - sx[j - 1] * sg[j - 1];
            hd[j] = s;
        }
    }
    __syncthreads();
    ss_vbox(hs, x, r0, acc[4]);

    float m1[5][4];
#pragma unroll
    for (int p = 0; p < 5; ++p) {
        float h3[6];
#pragma unroll
        for (int j = 0; j < 6; ++j) {
            int bb = (r0 + 4 + j) * PW + (x + 7);
            float s = 0.f;
#pragma unroll
            for (int i = 0; i < 3; ++i) {
                float vx = arrs[bb + i], vg = arrs[SSZ + bb + i];
                float v = (p == 0) ? vx : (p == 1) ? vg : (p == 2) ? vx * vx
                          : (p == 3) ? vg * vg : vx * vg;
                s += v;
            }
            h3[j] = s;
        }
#pragma unroll
        for (int j = 0; j < 4; ++j)
            m1[p][j] = (h3[j] + h3[j + 1] + h3[j + 2]) * (1.f / 9.f);
    }

    float l1 = 0.f, l2 = 0.f;
    float outv[5][4];
#pragma unroll
    for (int j = 0; j < 4; ++j) {
        float mux = acc[0][j], mug = acc[1][j], mxx = acc[2][j], mgg = acc[3][j], mxy = acc[4][j];
        float sx2 = fmaxf(mxx - mux * mux, 0.f);
        float sg2 = fmaxf(mgg - mug * mug, 0.f);
        float sxy = mxy - mux * mug;
        float num = (2.f * mux * mug + C1C) * (2.f * sxy + C2C);
        float den = (mux * mux + mug * mug + C1C) * (sx2 + sg2 + C2C);
        float tr_ = fminf(fmaxf((num / (den + DEN_EPS) + 1.f) * 0.5f, 0.f), 1.f);

        float n0 = m1[0][j], n1 = m1[1][j], n2 = m1[2][j], n3 = m1[3][j], n4 = m1[4][j];
        float sx21 = fmaxf(n2 - n0 * n0, 0.f);
        float sg21 = fmaxf(n3 - n1 * n1, 0.f);
        float sxy1 = n4 - n0 * n1;
        float num1 = (2.f * n0 * n1 + C1C) * (2.f * sxy1 + C2C);
        float den1 = (n0 * n0 + n1 * n1 + C1C) * (sx21 + sg21 + C2C);
        float t1_ = fminf(fmaxf((num1 / (den1 + DEN_EPS) + 1.f) * 0.5f, 0.f), 1.f);

        float chig_ = sqrtf(sg21 + EPSC) * sqrtf(sg2 + EPSC);
        float nu_ = fmaxf(t1_ * tr_, 0.f);
        outv[0][j] = mug; outv[1][j] = sg2; outv[2][j] = tr_;
        outv[3][j] = chig_; outv[4][j] = nu_;
        l1 += 1.f / (chig_ + EPSC);
        l2 += 1.f / (nu_ + THETAC);
    }
#pragma unroll
    for (int j = 0; j < 4; ++j) {
        int gp = b * HW + (ty0 + r0 + j) * Wn + (tx0 + x);
        muG[gp] = outv[0][j];
        varGr[gp] = outv[1][j];
        taur[gp] = outv[2][j];
        chig[gp] = outv[3][j];
        nu[gp] = outv[4][j];
    }
    __syncthreads();
    red1[t] = l1; red2[t] = l2;
    __syncthreads();
    for (int s = 128; s > 0; s >>= 1) {
        if (t < s) { red1[t] += red1[t + s]; red2[t] += red2[t + s]; }
        __syncthreads();
    }
    if (t == 0) {
        ps1[b * NT + blockIdx.x] = red1[0];
        ps2[b * NT + blockIdx.x] = red2[0];
    }
}

// ---------------- K red ----------------
__global__ void __launch_bounds__(256) k_red(
        const float* __restrict__ psum, const float* __restrict__ pmin,
        const float* __restrict__ s1, const float* __restrict__ s2,
        float* __restrict__ sc) {
    __shared__ float a1[256], a2[256];
    int t = threadIdx.x;
    if (blockIdx.x < 4) {
        int b = blockIdx.x;
        a1[t] = psum[b * 256 + t];
        a2[t] = pmin[b * 256 + t];
        __syncthreads();
        for (int s = 128; s > 0; s >>= 1) {
            if (t < s) { a1[t] += a1[t + s]; a2[t] = fminf(a2[t], a2[t + s]); }
            __syncthreads();
        }
        if (t == 0) {
            float mu = a1[0] / (float)HW;
            sc[b] = mu;
            sc[4 + b] = fmaxf(mu - a2[0], EPSC);
        }
    } else {
        int b = blockIdx.x - 4;
        a1[t] = s1[b * 256 + t];
        a2[t] = s2[b * 256 + t];
        __syncthreads();
        for (int s = 128; s > 0; s >>= 1) {
            if (t < s) { a1[t] += a1[t + s]; a2[t] += a2[t + s]; }
            __syncthreads();
        }
        if (t == 0) {
            sc[8 + b] = a1[0] / (float)HW;
            sc[12 + b] = a2[0] / (float)HW;
        }
    }
}

// ---------------- K4: packed (P, invD, muG) plane, 4-wide ----------------
__global__ void __launch_bounds__(256) k_pd(
        const float* __restrict__ chi, const float* __restrict__ chig,
        const float* __restrict__ nu, const float* __restrict__ taur,
        const float* __restrict__ vr, const float* __restrict__ muG,
        const float* __restrict__ sc, float4* __restrict__ PDM) {
    int i = blockIdx.x * 256 + threadIdx.x;
    int p0 = i * 4;
    int b = p0 >> 18;
    float mu = sc[b], eta = sc[4 + b], imc = sc[8 + b], imn = sc[12 + b];
    float4 c4 = ((const float4*)chi)[i];
    float4 cg4 = ((const float4*)chig)[i];
    float4 nu4 = ((const float4*)nu)[i];
    float4 tr4 = ((const float4*)taur)[i];
    float4 vr4 = ((const float4*)vr)[i];
    float4 mg4 = ((const float4*)muG)[i];
    float cc[4] = {c4.x, c4.y, c4.z, c4.w};
    float gg[4] = {cg4.x, cg4.y, cg4.z, cg4.w};
    float nn[4] = {nu4.x, nu4.y, nu4.z, nu4.w};
    float tt[4] = {tr4.x, tr4.y, tr4.z, tr4.w};
    float vv[4] = {vr4.x, vr4.y, vr4.z, vr4.w};
    float mm[4] = {mg4.x, mg4.y, mg4.z, mg4.w};
#pragma unroll
    for (int j = 0; j < 4; ++j) {
        float gamma = 1.f / (1.f + expf(-eta * (cc[j] - mu)));
        float GG = (gg[j] + EPSC) * imc;
        float w_e = 1.0f / (GG + EPSC);
        float GS = (nn[j] + THETAC) * imn;
        float w_s = gamma / (GS + EPSC);
        float P = w_e * gamma + w_s * tt[j];
        float D = vv[j] + EPSC + w_e + w_s + EPSC;
        PDM[p0 + j] = make_float4(P, 1.0f / D, mm[j], 0.f);
    }
}

// ---------------- K5: per-channel a,b (R6 structure + invD + unified staging) ----------------
__global__ void __launch_bounds__(256) k_ab(
        const float* __restrict__ X, const float* __restrict__ G,
        const float4* __restrict__ PDM, unsigned int* __restrict__ AB) {
    __shared__ float s0[SSZ], s1[SSZ];   // X, X*G (48-wide window, pitch 49)
    __shared__ float h[HSZ];
    int t = threadIdx.x;
    int pc = blockIdx.y, b = pc >> 4;
    int tile = swz_tile(blockIdx.x);
    int tx0 = (tile & 15) * TS, ty0 = (tile >> 4) * TS;
    int x = t & 31, wg = t >> 5, r0 = wg * 4;
    // prefetch epilogue operands (latency hides under staging/hbox)
    const float4* Pp = PDM + (size_t)b * HW;
    int pbase = (ty0 + r0) * Wn + tx0 + x;
    float4 pdm[4];
#pragma unroll
    for (int j = 0; j < 4; ++j) pdm[j] = Pp[pbase + j * Wn];

    const float* Xp = X + (size_t)pc * HW;
    const float* Gp = G + (size_t)b * HW;
    // unified staging: per-chunk validity, vec4 fast path
    for (int u = t; u < HALO * 12; u += 256) {
        int ly = u / 12, k = u - ly * 12;
        int gy = refl(ty0 - 5 + ly, Hn);
        int col = tx0 - 8 + 4 * k;
        int o = ly * PW + 4 * k;
        if (col >= 0 && col <= Wn - 4) {
            float4 xv = *(const float4*)(Xp + gy * Wn + col);
            float4 gv = *(const float4*)(Gp + gy * Wn + col);
            s0[o] = xv.x; s0[o + 1] = xv.y; s0[o + 2] = xv.z; s0[o + 3] = xv.w;
            s1[o] = xv.x * gv.x; s1[o + 1] = xv.y * gv.y;
            s1[o + 2] = xv.z * gv.z; s1[o + 3] = xv.w * gv.w;
        } else {
#pragma unroll
            for (int i = 0; i < 4; ++i) {
                int gx = refl(col + i, Wn);
                float xv = Xp[gy * Wn + gx], gv = Gp[gy * Wn + gx];
                s0[o + i] = xv;
                s1[o + i] = xv * gv;
            }
        }
    }
    __syncthreads();
    hboxp(s0, h, t);
    __syncthreads();
    float mx[4];
    vbox4(h, x, r0, mx);
    __syncthreads();
    hboxp(s1, h, t);
    __syncthreads();
    float mxg[4];
    vbox4(h, x, r0, mxg);

    unsigned int* Ap = AB + (size_t)pc * HW;
#pragma unroll
    for (int j = 0; j < 4; ++j) {
        float a = (mxg[j] - pdm[j].z * mx[j] + pdm[j].x) * pdm[j].y;  // *invD
        float bb = mx[j] - a * pdm[j].z;
        Ap[pbase + j * Wn] = bf16pack(a, bb);
    }
}

// ---------------- K6: out = box11(a)*G + box11(b) (packed su, 2 barriers) ----------------
__global__ void __launch_bounds__(256) k_out(
        const unsigned int* __restrict__ AB, const float* __restrict__ G,
        float* __restrict__ out) {
    __shared__ unsigned int su[SSZ];     // packed (a,b), pitch 49
    __shared__ float h0[HSZ], h1[HSZ];
    int t = threadIdx.x;
    int pc = blockIdx.y, b = pc >> 4;
    int tile = swz_tile(blockIdx.x);
    int tx0 = (tile & 15) * TS, ty0 = (tile >> 4) * TS;
    int x = t & 31, wg = t >> 5, r0 = wg * 4;
    // prefetch G for epilogue
    const float* Gp = G + (size_t)b * HW;
    int pbase = (ty0 + r0) * Wn + tx0 + x;
    float gv[4];
#pragma unroll
    for (int j = 0; j < 4; ++j) gv[j] = Gp[pbase + j * Wn];

    const unsigned int* Ap = AB + (size_t)pc * HW;
    // unified staging: per-chunk validity, uint4 fast path
    for (int u = t; u < HALO * 12; u += 256) {
        int ly = u / 12, k = u - ly * 12;
        int gy = refl(ty0 - 5 + ly, Hn);
        int col = tx0 - 8 + 4 * k;
        int o = ly * PW + 4 * k;
        if (col >= 0 && col <= Wn - 4) {
            uint4 v = *(const uint4*)(Ap + gy * Wn + col);
            su[o] = v.x; su[o + 1] = v.y; su[o + 2] = v.z; su[o + 3] = v.w;
        } else {
#pragma unroll
            for (int i = 0; i < 4; ++i) {
                int gx = refl(col + i, Wn);
                su[o + i] = Ap[gy * Wn + gx];
            }
        }
    }
    __syncthreads();

    // merged hbox with bf16 unpack at tap: 168 tasks, both planes per read
    if (t < 168) {
        int y = t >> 2, c = t & 3;
        const unsigned int* src = su + y * PW + 8 * c + 3;
        float* d0 = h0 + y * HP + 8 * c;
        float* d1 = h1 + y * HP + 8 * c;
        unsigned int u0 = src[0];
        float a0 = bflo(u0), a1 = bfhi(u0);
#pragma unroll
        for (int dx = 1; dx < K; ++dx) {
            unsigned int u = src[dx];
            a0 += bflo(u); a1 += bfhi(u);
        }
        d0[0] = a0; d1[0] = a1;
#pragma unroll
        for (int j = 1; j < 8; ++j) {
            unsigned int un = src[j + 10], uo = src[j - 1];
            a0 += bflo(un) - bflo(uo);
            a1 += bfhi(un) - bfhi(uo);
            d0[j] = a0; d1[j] = a1;
        }
    }
    __syncthreads();

    float ma[4], mb[4];
    vbox4(h0, x, r0, ma);
    vbox4(h1, x, r0, mb);

    float* op = out + (size_t)pc * HW;
#pragma unroll
    for (int j = 0; j < 4; ++j)
        op[pbase + j * Wn] = ma[j] * gv[j] + mb[j];
}

extern "C" void kernel_launch(void* const* d_in, const int* in_sizes, int n_in,
                              void* d_out, int out_size, void* d_ws, size_t ws_size,
                              hipStream_t stream) {
    const float* X = (const float*)d_in[0];
    const float* G = (const float*)d_in[1];
    float* out = (float*)d_out;
    float* ws = (float*)d_ws;

    float* Xs   = ws + 0 * (size_t)NP;
    float* chi  = ws + 1 * (size_t)NP;
    float* taur = ws + 2 * (size_t)NP;
    float* vr   = ws + 3 * (size_t)NP;
    float* muG  = ws + 4 * (size_t)NP;
    float* chig = ws + 5 * (size_t)NP;
    float* nu   = ws + 6 * (size_t)NP;
    float4* PDM = (float4*)(ws + 7 * (size_t)NP);            // 4*NP floats
    unsigned int* AB = (unsigned int*)(ws + 11 * (size_t)NP); // NX uints
    float* psum = ws + 43 * (size_t)NP;
    float* pmin = psum + 1024;
    float* ps1  = pmin + 1024;
    float* ps2  = ps1 + 1024;
    float* sc   = ps2 + 1024;   // 16 scalars

    dim3 blk(256);
    k_xschi<<<2048, blk, 0, stream>>>(X, G, Xs, chi, psum, pmin);

    dim3 gplane(NT, Bn);
    k_ssim<<<gplane, blk, 0, stream>>>(Xs, G, muG, vr, taur, chig, nu, ps1, ps2);
    k_red<<<8, blk, 0, stream>>>(psum, pmin, ps1, ps2, sc);
    k_pd<<<(NP / 4) / 256, blk, 0, stream>>>(chi, chig, nu, taur, vr, muG, sc, PDM);

    dim3 gchan(NT, Bn * Cn);
    k_ab<<<gchan, blk, 0, stream>>>(X, G, PDM, AB);
    k_out<<<gchan, blk, 0, stream>>>(AB, G, out);
}

// Round 11
// 110.716 us; speedup vs baseline: 1.2481x; 1.0052x over previous
//
#include <hip/hip_runtime.h>
#include <math.h>

#define EPSC 1e-6f
#define THETAC 1e-3f
#define C1C 1e-4f
#define C2C 9e-4f
#define DEN_EPS 1e-12f

constexpr int Bn = 4, Cn = 16, Hn = 512, Wn = 512;
constexpr int HW = Hn * Wn;          // 262144 = 2^18
constexpr int NP = Bn * HW;          // 1048576
constexpr int TS = 32, RAD = 5, K = 11;
constexpr int HALO = TS + 2 * RAD;   // 42
constexpr int HP = 33;               // horizontal-sum pitch (linear, conflict-free)
constexpr int HSZ = HALO * HP;       // 1386
constexpr int tiles_x = Wn / TS;     // 16
constexpr int NT = tiles_x * (Hn / TS); // 256

// 48-wide aligned window, pitch 49 (all tiled kernels)
constexpr int PW = 49;
constexpr int SSZ = HALO * PW;       // 2058

__device__ __forceinline__ int refl(int i, int n) {
    if (i < 0) i = -i;
    if (i >= n) i = 2 * n - 2 - i;
    return i;
}

__device__ __forceinline__ int swz_tile(int x) { return (x & 7) * (NT / 8) + (x >> 3); }

__device__ __forceinline__ unsigned int bf16pack(float a, float b) {
    unsigned int ua = __float_as_uint(a), ub = __float_as_uint(b);
    ua += 0x7FFFu + ((ua >> 16) & 1u);
    ub += 0x7FFFu + ((ub >> 16) & 1u);
    return (ua >> 16) | (ub & 0xFFFF0000u);
}
__device__ __forceinline__ float bflo(unsigned int v) { return __uint_as_float(v << 16); }
__device__ __forceinline__ float bfhi(unsigned int v) { return __uint_as_float(v & 0xFFFF0000u); }

// vbox4 over linear pitch-33 h
__device__ __forceinline__ void vbox4(const float* h, int x, int r0, float m[4]) {
    const float inv = 1.f / 121.f;
    const float* hb = h + r0 * HP + x;
    float s = hb[0];
#pragma unroll
    for (int dy = 1; dy < K; ++dy) s += hb[dy * HP];
    m[0] = s * inv;
#pragma unroll
    for (int j = 1; j < 4; ++j) {
        s += hb[(j + 10) * HP] - hb[(j - 1) * HP];
        m[j] = s * inv;
    }
}

// merged hbox over packed bf16-pair window: 168 tasks, both planes per read
__device__ __forceinline__ void hbox_packed(const unsigned int* su, float* h0, float* h1, int t) {
    if (t < 168) {
        int y = t >> 2, c = t & 3;
        const unsigned int* src = su + y * PW + 8 * c + 3;
        float* d0 = h0 + y * HP + 8 * c;
        float* d1 = h1 + y * HP + 8 * c;
        unsigned int u0 = src[0];
        float a0 = bflo(u0), a1 = bfhi(u0);
#pragma unroll
        for (int dx = 1; dx < K; ++dx) {
            unsigned int u = src[dx];
            a0 += bflo(u); a1 += bfhi(u);
        }
        d0[0] = a0; d1[0] = a1;
#pragma unroll
        for (int j = 1; j < 8; ++j) {
            unsigned int un = src[j + 10], uo = src[j - 1];
            a0 += bflo(un) - bflo(uo);
            a1 += bfhi(un) - bfhi(uo);
            d0[j] = a0; d1[j] = a1;
        }
    }
}

// ---------------- K1: merged Xs (channel mean) + chi (+partial reductions) ----------------
__global__ void __launch_bounds__(256) k_xschi(
        const float* __restrict__ X, const float* __restrict__ G,
        float* __restrict__ Xs, float* __restrict__ chi,
        float* __restrict__ psum, float* __restrict__ pmin) {
    int t = threadIdx.x;
    if (blockIdx.x < 1024) {
        constexpr int HW4 = HW / 4;
        int i = blockIdx.x * 256 + t;
        int b = i / HW4, off = i - b * HW4;
        const float4* xp = (const float4*)(X + (size_t)b * Cn * HW) + off;
        float4 s = make_float4(0.f, 0.f, 0.f, 0.f);
#pragma unroll
        for (int c = 0; c < Cn; ++c) {
            float4 v = xp[(size_t)c * HW4];
            s.x += v.x; s.y += v.y; s.z += v.z; s.w += v.w;
        }
        const float sc = 1.0f / Cn;
        s.x *= sc; s.y *= sc; s.z *= sc; s.w *= sc;
        ((float4*)Xs)[i] = s;
        return;
    }
    __shared__ float ssum[256], smin[256];
    int bid = blockIdx.x - 1024;
    int base = bid * 1024;
    float ls = 0.f, lm = 1e30f;
#pragma unroll
    for (int k = 0; k < 4; ++k) {
        int p = base + t + k * 256;
        int off = p & (HW - 1);
        int y = off / Wn, x = off & (Wn - 1);
        float g = G[p];
        float gx = (x < Wn - 1) ? G[p + 1] - g : 0.f;
        float gy = (y < Hn - 1) ? G[p + Wn] - g : 0.f;
        float c = sqrtf(gx * gx + gy * gy + EPSC);
        chi[p] = c;
        ls += c;
        lm = fminf(lm, c);
    }
    ssum[t] = ls; smin[t] = lm;
    __syncthreads();
    for (int s = 128; s > 0; s >>= 1) {
        if (t < s) { ssum[t] += ssum[t + s]; smin[t] = fminf(smin[t], smin[t + s]); }
        __syncthreads();
    }
    if (t == 0) { psum[bid] = ssum[0]; pmin[bid] = smin[0]; }
}

// k_ssim hbox over 2 planes at pitch 49 (+3 offset), optionally squared
template <bool SQ>
__device__ __forceinline__ void ss_hbox2(const float* arrs, float* hs, int t) {
    if (t < 168) {
        int pl = t / 84, rem = t - pl * 84;
        int y = rem >> 1, xh = (rem & 1) << 4;
        const float* src = arrs + pl * SSZ + y * PW + xh + 3;
        float* hd = hs + pl * HSZ + y * HP + xh;
        float v = src[0];
        float s = SQ ? v * v : v;
#pragma unroll
        for (int dx = 1; dx < K; ++dx) { float u = src[dx]; s += SQ ? u * u : u; }
        hd[0] = s;
#pragma unroll
        for (int j = 1; j < 16; ++j) {
            float un = src[j + 10], uo = src[j - 1];
            s += (SQ ? un * un : un) - (SQ ? uo * uo : uo);
            hd[j] = s;
        }
    }
}

__device__ __forceinline__ void ss_vbox(const float* hs, int x, int r0, float m[4]) {
    const float inv_area = 1.f / (float)(K * K);
    const float* hb = hs + r0 * HP + x;
    float s = hb[0];
#pragma unroll
    for (int dy = 1; dy < K; ++dy) s += hb[dy * HP];
    m[0] = s * inv_area;
#pragma unroll
    for (int j = 1; j < 4; ++j) {
        s += hb[(j + 10) * HP] - hb[(j - 1) * HP];
        m[j] = s * inv_area;
    }
}

// ---------------- K3: merged ssim r=5 & r=1 + plane outputs + reductions ----------------
__global__ void __launch_bounds__(256) k_ssim(
        const float* __restrict__ Xs, const float* __restrict__ G,
        float* __restrict__ muG, float* __restrict__ varGr, float* __restrict__ taur,
        float* __restrict__ chig, float* __restrict__ nu,
        float* __restrict__ ps1, float* __restrict__ ps2) {
    __shared__ float arrs[2 * SSZ];   // x, g windows (pitch 49, 48-wide aligned)
    __shared__ float hs[2 * HSZ];
    float* red1 = hs;
    float* red2 = hs + HSZ;
    int t = threadIdx.x;
    int b = blockIdx.y;
    int tile = swz_tile(blockIdx.x);
    int tx0 = (tile % tiles_x) * TS, ty0 = (tile / tiles_x) * TS;
    const float* Xp = Xs + (size_t)b * HW;
    const float* Gp = G + (size_t)b * HW;
    for (int u = t; u < HALO * 12; u += 256) {
        int ly = u / 12, k = u - ly * 12;
        int gy = refl(ty0 - 5 + ly, Hn);
        int col = tx0 - 8 + 4 * k;
        int o = ly * PW + 4 * k;
        if (col >= 0 && col <= Wn - 4) {
            float4 xv = *(const float4*)(Xp + gy * Wn + col);
            float4 gv = *(const float4*)(Gp + gy * Wn + col);
            arrs[o] = xv.x; arrs[o + 1] = xv.y; arrs[o + 2] = xv.z; arrs[o + 3] = xv.w;
            arrs[SSZ + o] = gv.x; arrs[SSZ + o + 1] = gv.y;
            arrs[SSZ + o + 2] = gv.z; arrs[SSZ + o + 3] = gv.w;
        } else {
#pragma unroll
            for (int i = 0; i < 4; ++i) {
                int gx = refl(col + i, Wn);
                arrs[o + i] = Xp[gy * Wn + gx];
                arrs[SSZ + o + i] = Gp[gy * Wn + gx];
            }
        }
    }
    __syncthreads();

    int x = t & 31, g = t >> 5, r0 = g * 4;
    float acc[5][4];
    ss_hbox2<false>(arrs, hs, t);
    __syncthreads();
    ss_vbox(hs, x, r0, acc[0]);
    ss_vbox(hs + HSZ, x, r0, acc[1]);
    __syncthreads();
    ss_hbox2<true>(arrs, hs, t);
    __syncthreads();
    ss_vbox(hs, x, r0, acc[2]);
    ss_vbox(hs + HSZ, x, r0, acc[3]);
    __syncthreads();
    if (t < 168) {   // x*g plane, 8-wide chunks
        int y = t >> 2, c = t & 3;
        const float* sx = arrs + y * PW + 8 * c + 3;
        const float* sg = arrs + SSZ + y * PW + 8 * c + 3;
        float* hd = hs + y * HP + 8 * c;
        float s = sx[0] * sg[0];
#pragma unroll
        for (int dx = 1; dx < K; ++dx) s += sx[dx] * sg[dx];
        hd[0] = s;
#pragma unroll
        for (int j = 1; j < 8; ++j) {
            s += sx[j + 10] * sg[j + 10] - sx[j - 1] * sg[j - 1];
            hd[j] = s;
        }
    }
    __syncthreads();
    ss_vbox(hs, x, r0, acc[4]);

    float m1[5][4];
#pragma unroll
    for (int p = 0; p < 5; ++p) {
        float h3[6];
#pragma unroll
        for (int j = 0; j < 6; ++j) {
            int bb = (r0 + 4 + j) * PW + (x + 7);
            float s = 0.f;
#pragma unroll
            for (int i = 0; i < 3; ++i) {
                float vx = arrs[bb + i], vg = arrs[SSZ + bb + i];
                float v = (p == 0) ? vx : (p == 1) ? vg : (p == 2) ? vx * vx
                          : (p == 3) ? vg * vg : vx * vg;
                s += v;
            }
            h3[j] = s;
        }
#pragma unroll
        for (int j = 0; j < 4; ++j)
            m1[p][j] = (h3[j] + h3[j + 1] + h3[j + 2]) * (1.f / 9.f);
    }

    float l1 = 0.f, l2 = 0.f;
    float outv[5][4];
#pragma unroll
    for (int j = 0; j < 4; ++j) {
        float mux = acc[0][j], mug = acc[1][j], mxx = acc[2][j], mgg = acc[3][j], mxy = acc[4][j];
        float sx2 = fmaxf(mxx - mux * mux, 0.f);
        float sg2 = fmaxf(mgg - mug * mug, 0.f);
        float sxy = mxy - mux * mug;
        float num = (2.f * mux * mug + C1C) * (2.f * sxy + C2C);
        float den = (mux * mux + mug * mug + C1C) * (sx2 + sg2 + C2C);
        float tr_ = fminf(fmaxf((num / (den + DEN_EPS) + 1.f) * 0.5f, 0.f), 1.f);

        float n0 = m1[0][j], n1 = m1[1][j], n2 = m1[2][j], n3 = m1[3][j], n4 = m1[4][j];
        float sx21 = fmaxf(n2 - n0 * n0, 0.f);
        float sg21 = fmaxf(n3 - n1 * n1, 0.f);
        float sxy1 = n4 - n0 * n1;
        float num1 = (2.f * n0 * n1 + C1C) * (2.f * sxy1 + C2C);
        float den1 = (n0 * n0 + n1 * n1 + C1C) * (sx21 + sg21 + C2C);
        float t1_ = fminf(fmaxf((num1 / (den1 + DEN_EPS) + 1.f) * 0.5f, 0.f), 1.f);

        float chig_ = sqrtf(sg21 + EPSC) * sqrtf(sg2 + EPSC);
        float nu_ = fmaxf(t1_ * tr_, 0.f);
        outv[0][j] = mug; outv[1][j] = sg2; outv[2][j] = tr_;
        outv[3][j] = chig_; outv[4][j] = nu_;
        l1 += 1.f / (chig_ + EPSC);
        l2 += 1.f / (nu_ + THETAC);
    }
#pragma unroll
    for (int j = 0; j < 4; ++j) {
        int gp = b * HW + (ty0 + r0 + j) * Wn + (tx0 + x);
        muG[gp] = outv[0][j];
        varGr[gp] = outv[1][j];
        taur[gp] = outv[2][j];
        chig[gp] = outv[3][j];
        nu[gp] = outv[4][j];
    }
    __syncthreads();
    red1[t] = l1; red2[t] = l2;
    __syncthreads();
    for (int s = 128; s > 0; s >>= 1) {
        if (t < s) { red1[t] += red1[t + s]; red2[t] += red2[t + s]; }
        __syncthreads();
    }
    if (t == 0) {
        ps1[b * NT + blockIdx.x] = red1[0];
        ps2[b * NT + blockIdx.x] = red2[0];
    }
}

// ---------------- K red ----------------
__global__ void __launch_bounds__(256) k_red(
        const float* __restrict__ psum, const float* __restrict__ pmin,
        const float* __restrict__ s1, const float* __restrict__ s2,
        float* __restrict__ sc) {
    __shared__ float a1[256], a2[256];
    int t = threadIdx.x;
    if (blockIdx.x < 4) {
        int b = blockIdx.x;
        a1[t] = psum[b * 256 + t];
        a2[t] = pmin[b * 256 + t];
        __syncthreads();
        for (int s = 128; s > 0; s >>= 1) {
            if (t < s) { a1[t] += a1[t + s]; a2[t] = fminf(a2[t], a2[t + s]); }
            __syncthreads();
        }
        if (t == 0) {
            float mu = a1[0] / (float)HW;
            sc[b] = mu;
            sc[4 + b] = fmaxf(mu - a2[0], EPSC);
        }
    } else {
        int b = blockIdx.x - 4;
        a1[t] = s1[b * 256 + t];
        a2[t] = s2[b * 256 + t];
        __syncthreads();
        for (int s = 128; s > 0; s >>= 1) {
            if (t < s) { a1[t] += a1[t + s]; a2[t] += a2[t + s]; }
            __syncthreads();
        }
        if (t == 0) {
            sc[8 + b] = a1[0] / (float)HW;
            sc[12 + b] = a2[0] / (float)HW;
        }
    }
}

// ---------------- K4: packed (P, invD, muG) plane, 4-wide ----------------
__global__ void __launch_bounds__(256) k_pd(
        const float* __restrict__ chi, const float* __restrict__ chig,
        const float* __restrict__ nu, const float* __restrict__ taur,
        const float* __restrict__ vr, const float* __restrict__ muG,
        const float* __restrict__ sc, float4* __restrict__ PDM) {
    int i = blockIdx.x * 256 + threadIdx.x;
    int p0 = i * 4;
    int b = p0 >> 18;
    float mu = sc[b], eta = sc[4 + b], imc = sc[8 + b], imn = sc[12 + b];
    float4 c4 = ((const float4*)chi)[i];
    float4 cg4 = ((const float4*)chig)[i];
    float4 nu4 = ((const float4*)nu)[i];
    float4 tr4 = ((const float4*)taur)[i];
    float4 vr4 = ((const float4*)vr)[i];
    float4 mg4 = ((const float4*)muG)[i];
    float cc[4] = {c4.x, c4.y, c4.z, c4.w};
    float gg[4] = {cg4.x, cg4.y, cg4.z, cg4.w};
    float nn[4] = {nu4.x, nu4.y, nu4.z, nu4.w};
    float tt[4] = {tr4.x, tr4.y, tr4.z, tr4.w};
    float vv[4] = {vr4.x, vr4.y, vr4.z, vr4.w};
    float mm[4] = {mg4.x, mg4.y, mg4.z, mg4.w};
#pragma unroll
    for (int j = 0; j < 4; ++j) {
        float gamma = 1.f / (1.f + expf(-eta * (cc[j] - mu)));
        float GG = (gg[j] + EPSC) * imc;
        float w_e = 1.0f / (GG + EPSC);
        float GS = (nn[j] + THETAC) * imn;
        float w_s = gamma / (GS + EPSC);
        float P = w_e * gamma + w_s * tt[j];
        float D = vv[j] + EPSC + w_e + w_s + EPSC;
        PDM[p0 + j] = make_float4(P, 1.0f / D, mm[j], 0.f);
    }
}

// ---------------- K5: per-channel a,b (packed bf16 window, 2 barriers) ----------------
__global__ void __launch_bounds__(256) k_ab(
        const float* __restrict__ X, const float* __restrict__ G,
        const float4* __restrict__ PDM, unsigned int* __restrict__ AB) {
    __shared__ unsigned int su[SSZ];     // packed (X, X*G) bf16 pairs, pitch 49
    __shared__ float h0[HSZ], h1[HSZ];
    int t = threadIdx.x;
    int pc = blockIdx.y, b = pc >> 4;
    int tile = swz_tile(blockIdx.x);
    int tx0 = (tile & 15) * TS, ty0 = (tile >> 4) * TS;
    int x = t & 31, wg = t >> 5, r0 = wg * 4;
    // prefetch epilogue operands (latency hides under staging/hbox)
    const float4* Pp = PDM + (size_t)b * HW;
    int pbase = (ty0 + r0) * Wn + tx0 + x;
    float4 pdm[4];
#pragma unroll
    for (int j = 0; j < 4; ++j) pdm[j] = Pp[pbase + j * Wn];

    const float* Xp = X + (size_t)pc * HW;
    const float* Gp = G + (size_t)b * HW;
    // unified staging: per-chunk validity, vec4 fast path; pack (X, X*G) -> bf16 pair
    for (int u = t; u < HALO * 12; u += 256) {
        int ly = u / 12, k = u - ly * 12;
        int gy = refl(ty0 - 5 + ly, Hn);
        int col = tx0 - 8 + 4 * k;
        int o = ly * PW + 4 * k;
        if (col >= 0 && col <= Wn - 4) {
            float4 xv = *(const float4*)(Xp + gy * Wn + col);
            float4 gv = *(const float4*)(Gp + gy * Wn + col);
            su[o]     = bf16pack(xv.x, xv.x * gv.x);
            su[o + 1] = bf16pack(xv.y, xv.y * gv.y);
            su[o + 2] = bf16pack(xv.z, xv.z * gv.z);
            su[o + 3] = bf16pack(xv.w, xv.w * gv.w);
        } else {
#pragma unroll
            for (int i = 0; i < 4; ++i) {
                int gx = refl(col + i, Wn);
                float xv = Xp[gy * Wn + gx], gv = Gp[gy * Wn + gx];
                su[o + i] = bf16pack(xv, xv * gv);
            }
        }
    }
    __syncthreads();
    hbox_packed(su, h0, h1, t);   // h0 = hsum(X), h1 = hsum(X*G)
    __syncthreads();

    float mx[4], mxg[4];
    vbox4(h0, x, r0, mx);
    vbox4(h1, x, r0, mxg);

    unsigned int* Ap = AB + (size_t)pc * HW;
#pragma unroll
    for (int j = 0; j < 4; ++j) {
        float a = (mxg[j] - pdm[j].z * mx[j] + pdm[j].x) * pdm[j].y;  // *invD
        float bb = mx[j] - a * pdm[j].z;
        Ap[pbase + j * Wn] = bf16pack(a, bb);
    }
}

// ---------------- K6: out = box11(a)*G + box11(b) (packed su, 2 barriers) ----------------
__global__ void __launch_bounds__(256) k_out(
        const unsigned int* __restrict__ AB, const float* __restrict__ G,
        float* __restrict__ out) {
    __shared__ unsigned int su[SSZ];     // packed (a,b), pitch 49
    __shared__ float h0[HSZ], h1[HSZ];
    int t = threadIdx.x;
    int pc = blockIdx.y, b = pc >> 4;
    int tile = swz_tile(blockIdx.x);
    int tx0 = (tile & 15) * TS, ty0 = (tile >> 4) * TS;
    int x = t & 31, wg = t >> 5, r0 = wg * 4;
    // prefetch G for epilogue
    const float* Gp = G + (size_t)b * HW;
    int pbase = (ty0 + r0) * Wn + tx0 + x;
    float gv[4];
#pragma unroll
    for (int j = 0; j < 4; ++j) gv[j] = Gp[pbase + j * Wn];

    const unsigned int* Ap = AB + (size_t)pc * HW;
    for (int u = t; u < HALO * 12; u += 256) {
        int ly = u / 12, k = u - ly * 12;
        int gy = refl(ty0 - 5 + ly, Hn);
        int col = tx0 - 8 + 4 * k;
        int o = ly * PW + 4 * k;
        if (col >= 0 && col <= Wn - 4) {
            uint4 v = *(const uint4*)(Ap + gy * Wn + col);
            su[o] = v.x; su[o + 1] = v.y; su[o + 2] = v.z; su[o + 3] = v.w;
        } else {
#pragma unroll
            for (int i = 0; i < 4; ++i) {
                int gx = refl(col + i, Wn);
                su[o + i] = Ap[gy * Wn + gx];
            }
        }
    }
    __syncthreads();
    hbox_packed(su, h0, h1, t);   // h0 = hsum(a), h1 = hsum(b)
    __syncthreads();

    float ma[4], mb[4];
    vbox4(h0, x, r0, ma);
    vbox4(h1, x, r0, mb);

    float* op = out + (size_t)pc * HW;
#pragma unroll
    for (int j = 0; j < 4; ++j)
        op[pbase + j * Wn] = ma[j] * gv[j] + mb[j];
}

extern "C" void kernel_launch(void* const* d_in, const int* in_sizes, int n_in,
                              void* d_out, int out_size, void* d_ws, size_t ws_size,
                              hipStream_t stream) {
    const float* X = (const float*)d_in[0];
    const float* G = (const float*)d_in[1];
    float* out = (float*)d_out;
    float* ws = (float*)d_ws;

    float* Xs   = ws + 0 * (size_t)NP;
    float* chi  = ws + 1 * (size_t)NP;
    float* taur = ws + 2 * (size_t)NP;
    float* vr   = ws + 3 * (size_t)NP;
    float* muG  = ws + 4 * (size_t)NP;
    float* chig = ws + 5 * (size_t)NP;
    float* nu   = ws + 6 * (size_t)NP;
    float4* PDM = (float4*)(ws + 7 * (size_t)NP);            // 4*NP floats
    unsigned int* AB = (unsigned int*)(ws + 11 * (size_t)NP); // NX uints
    float* psum = ws + 43 * (size_t)NP;
    float* pmin = psum + 1024;
    float* ps1  = pmin + 1024;
    float* ps2  = ps1 + 1024;
    float* sc   = ps2 + 1024;   // 16 scalars

    dim3 blk(256);
    k_xschi<<<2048, blk, 0, stream>>>(X, G, Xs, chi, psum, pmin);

    dim3 gplane(NT, Bn);
    k_ssim<<<gplane, blk, 0, stream>>>(Xs, G, muG, vr, taur, chig, nu, ps1, ps2);
    k_red<<<8, blk, 0, stream>>>(psum, pmin, ps1, ps2, sc);
    k_pd<<<(NP / 4) / 256, blk, 0, stream>>>(chi, chig, nu, taur, vr, muG, sc, PDM);

    dim3 gchan(NT, Bn * Cn);
    k_ab<<<gchan, blk, 0, stream>>>(X, G, PDM, AB);
    k_out<<<gchan, blk, 0, stream>>>(AB, G, out);
}